// Round 1
// baseline (161.305 us; speedup 1.0000x reference)
//
#include <hip/hip_runtime.h>

// ---------------------------------------------------------------------------
// Problem constants: B=16, T=2048, C=128, N=64, FFT length NF=4096
// ---------------------------------------------------------------------------

static __device__ __forceinline__ float2 cmulf(float2 a, float2 b) {
  return make_float2(a.x * b.x - a.y * b.y, a.x * b.y + a.y * b.x);
}

// Twiddle half-table for N=4096: tw[j] = e^{-2*pi*i*j/4096}, j in [0,2048)
static __device__ __forceinline__ void build_tw(float2* tw, int tid) {
  for (int j = tid; j < 2048; j += 256) {
    float sv, cv;
    sincospif(-(float)j * (1.0f / 2048.0f), &sv, &cv);
    tw[j] = make_float2(cv, sv);
  }
}

// DIF radix-2 (Gentleman-Sande): natural input -> bit-reversed output.
// CONJ=false: forward (e^{-}); CONJ=true: inverse kernel (e^{+}).
// TWSHIFT scales table index (0 for N=4096, 1 for N=2048).
template <int NPTS, bool CONJ, int TWSHIFT>
static __device__ __forceinline__ void dif_fft(float2* s, const float2* tw, int tid) {
  int step = 1;
  for (int m = NPTS >> 1; m >= 1; m >>= 1, step <<= 1) {
    for (int k = tid; k < (NPTS >> 1); k += 256) {
      int j = k & (m - 1);
      int i0 = ((k - j) << 1) + j;
      int i1 = i0 + m;
      float2 a = s[i0], b = s[i1];
      s[i0] = make_float2(a.x + b.x, a.y + b.y);
      float2 d = make_float2(a.x - b.x, a.y - b.y);
      float2 w = tw[(j * step) << TWSHIFT];
      if (CONJ) w.y = -w.y;
      s[i1] = cmulf(d, w);
    }
    __syncthreads();
  }
}

// DIT radix-2 inverse (Cooley-Tukey): bit-reversed input -> natural output, e^{+}.
template <int NPTS, int TWSHIFT>
static __device__ __forceinline__ void dit_ifft(float2* s, const float2* tw, int tid) {
  int step = NPTS >> 1;
  for (int m = 1; m <= (NPTS >> 1); m <<= 1, step >>= 1) {
    for (int k = tid; k < (NPTS >> 1); k += 256) {
      int j = k & (m - 1);
      int i0 = ((k - j) << 1) + j;
      int i1 = i0 + m;
      float2 w = tw[(j * step) << TWSHIFT];
      w.y = -w.y;
      float2 t = cmulf(s[i1], w);
      float2 a = s[i0];
      s[i0] = make_float2(a.x + t.x, a.y + t.y);
      s[i1] = make_float2(a.x - t.x, a.y - t.y);
    }
    __syncthreads();
  }
}

// ---------------------------------------------------------------------------
// Kernel 1: LayerNorm over channels + transpose (B,T,C) -> (B,C,T)
// grid = B * (T/32) = 1024, block = 256
// ---------------------------------------------------------------------------
__global__ __launch_bounds__(256) void k_ln_t(const float* __restrict__ x,
                                              const float* __restrict__ gamma,
                                              const float* __restrict__ beta,
                                              float* __restrict__ y_tr) {
  __shared__ float tile[32 * 129];
  __shared__ float sg[128], sb[128];
  const int tid = threadIdx.x;
  const int b = blockIdx.x >> 6;
  const int t0 = (blockIdx.x & 63) << 5;
  if (tid < 128) { sg[tid] = gamma[tid]; sb[tid] = beta[tid]; }
  const float* xb = x + ((size_t)b * 2048 + t0) * 128;
#pragma unroll
  for (int r = 0; r < 16; ++r) {
    int idx = tid + 256 * r;
    tile[(idx >> 7) * 129 + (idx & 127)] = xb[idx];
  }
  __syncthreads();
  const int row = tid >> 3, sgp = tid & 7;
  float sum = 0.f, sq = 0.f;
#pragma unroll
  for (int i = 0; i < 16; ++i) {
    float v = tile[row * 129 + sgp * 16 + i];
    sum += v;
    sq += v * v;
  }
  sum += __shfl_xor(sum, 1); sq += __shfl_xor(sq, 1);
  sum += __shfl_xor(sum, 2); sq += __shfl_xor(sq, 2);
  sum += __shfl_xor(sum, 4); sq += __shfl_xor(sq, 4);
  float mean = sum * (1.0f / 128.0f);
  float var = sq * (1.0f / 128.0f) - mean * mean;
  float rstd = 1.0f / sqrtf(var + 1e-5f);
#pragma unroll
  for (int i = 0; i < 16; ++i) {
    int cc = sgp * 16 + i;
    float v = tile[row * 129 + cc];
    tile[row * 129 + cc] = (v - mean) * rstd * sg[cc] + sb[cc];
  }
  __syncthreads();
  float* yb = y_tr + (size_t)b * 128 * 2048 + t0;
#pragma unroll
  for (int r = 0; r < 16; ++r) {
    int idx = tid + 256 * r;
    int cc = idx >> 5, tl = idx & 31;
    yb[(size_t)cc * 2048 + tl] = tile[tl * 129 + cc];
  }
}

// ---------------------------------------------------------------------------
// Kernel 2: at_roots (DPLR generating function at the 2048 unity roots)
// grid = 128 channels * 4 l-slabs = 512, block = 256; out layout (C, L)
// ---------------------------------------------------------------------------
__global__ __launch_bounds__(256) void k_ar(const float* __restrict__ Lr, const float* __restrict__ Li,
                                            const float* __restrict__ Pr, const float* __restrict__ Pi,
                                            const float* __restrict__ Br, const float* __restrict__ Bi,
                                            const float* __restrict__ Cr, const float* __restrict__ Ci,
                                            float2* __restrict__ arr) {
  __shared__ float2 sLam[64], sv00[64], sv01[64], sv10[64], sv11[64];
  const int c = blockIdx.x >> 2;
  const int slab = blockIdx.x & 3;
  const int tid = threadIdx.x;
  if (tid < 64) {
    int i = c * 64 + tid;
    float lr = fminf(Lr[i], 1e-4f), li = Li[i];
    float pr = Pr[i], pi = Pi[i];
    float br = Br[i], bi = Bi[i];
    float cr = Cr[i], ci = Ci[i];
    sLam[tid] = make_float2(lr, li);
    sv00[tid] = make_float2(cr * br + ci * bi, cr * bi - ci * br);  // conj(C)*B
    sv01[tid] = make_float2(cr * pr + ci * pi, cr * pi - ci * pr);  // conj(C)*P
    sv10[tid] = make_float2(pr * br + pi * bi, pr * bi - pi * br);  // conj(P)*B
    sv11[tid] = make_float2(pr * pr + pi * pi, 0.0f);               // conj(P)*P
  }
  __syncthreads();
#pragma unroll
  for (int kk = 0; kk < 2; ++kk) {
    int l = slab * 512 + tid + 256 * kk;
    float theta = (-6.2831855f * (float)l) * (1.0f / 2048.0f);
    float om_i, om_r;
    sincosf(theta, &om_i, &om_r);
    float pr_ = 1.0f + om_r, pi_ = om_i;   // 1 + Omega
    float mr_ = 1.0f - om_r, mi_ = -om_i;  // 1 - Omega
    float invd = 1.0f / (pr_ * pr_ + pi_ * pi_);
    float gr = 200.0f * ((mr_ * pr_ + mi_ * pi_) * invd);
    float gi = 200.0f * ((mi_ * pr_ - mr_ * pi_) * invd);
    float c2r = 2.0f * pr_ * invd, c2i = -2.0f * pi_ * invd;
    float s00r = 0.f, s00i = 0.f, s01r = 0.f, s01i = 0.f;
    float s10r = 0.f, s10i = 0.f, s11r = 0.f, s11i = 0.f;
#pragma unroll 8
    for (int n = 0; n < 64; ++n) {
      float2 lam = sLam[n];
      float dr = gr - lam.x, di = gi - lam.y;
      float idn = 1.0f / (dr * dr + di * di);
      float ir = dr * idn, ii = -di * idn;  // 1/(g - Lam)
      float2 v;
      v = sv00[n]; s00r += v.x * ir - v.y * ii; s00i += v.x * ii + v.y * ir;
      v = sv01[n]; s01r += v.x * ir - v.y * ii; s01i += v.x * ii + v.y * ir;
      v = sv10[n]; s10r += v.x * ir - v.y * ii; s10i += v.x * ii + v.y * ir;
      v = sv11[n]; s11r += v.x * ir - v.y * ii; s11i += v.x * ii + v.y * ir;
    }
    // r = 1/(1 + k11); at = c2 * (k00 - k01 * r * k10)
    float dr2 = 1.0f + s11r, di2 = s11i;
    float idn2 = 1.0f / (dr2 * dr2 + di2 * di2);
    float rr = dr2 * idn2, ri = -di2 * idn2;
    float t1r = s01r * rr - s01i * ri, t1i = s01r * ri + s01i * rr;
    float t2r = t1r * s10r - t1i * s10i, t2i = t1r * s10i + t1i * s10r;
    float fr = s00r - t2r, fi = s00i - t2i;
    arr[(size_t)c * 2048 + l] = make_float2(c2r * fr - c2i * fi, c2r * fi + c2i * fr);
  }
}

// ---------------------------------------------------------------------------
// Kernel 3: per channel: ifft_2048(at_roots).real -> zero-pad -> fft_4096
// Output kf in DIF bit-reversed order (consumed in the same order).
// grid = 128, block = 256, LDS = 48 KB
// ---------------------------------------------------------------------------
__global__ __launch_bounds__(256) void k_kf(const float2* __restrict__ arr, float2* __restrict__ kf) {
  __shared__ float2 tw[2048];
  __shared__ float2 s[4096];
  const int tid = threadIdx.x;
  const int c = blockIdx.x;
  build_tw(tw, tid);
  for (int k = tid; k < 2048; k += 256) s[2048 + k] = arr[(size_t)c * 2048 + k];
  __syncthreads();
  // inverse 2048-pt (unnormalized, e^{+}), result bit-reversed in upper half
  dif_fft<2048, true, 1>(s + 2048, tw, tid);
  // time-domain kernel (real, /2048) into lower half, natural order
#pragma unroll
  for (int kk = 0; kk < 8; ++kk) {
    int t = tid + 256 * kk;
    int r = (int)(__brev((unsigned)t) >> 21);
    s[t] = make_float2(s[2048 + r].x * (1.0f / 2048.0f), 0.0f);
  }
  __syncthreads();
#pragma unroll
  for (int kk = 0; kk < 8; ++kk) s[2048 + tid + 256 * kk] = make_float2(0.f, 0.f);
  __syncthreads();
  dif_fft<4096, false, 0>(s, tw, tid);
#pragma unroll
  for (int kk = 0; kk < 16; ++kk) {
    int m = tid + 256 * kk;
    kf[(size_t)c * 4096 + m] = s[m];
  }
}

// ---------------------------------------------------------------------------
// Kernel 4: per (b,c): FFT conv (fwd DIF -> spectral mult -> inv DIT),
// + D*y, exact GELU; h written in place over y. grid = B*C = 2048, block 256.
// ---------------------------------------------------------------------------
__global__ __launch_bounds__(256) void k_conv(float* __restrict__ y_tr,
                                              const float2* __restrict__ kf,
                                              const float* __restrict__ D) {
  __shared__ float2 tw[2048];
  __shared__ float2 s[4096];
  const int tid = threadIdx.x;
  const int bc = blockIdx.x;
  const int c = bc & 127;
  build_tw(tw, tid);
  float* row = y_tr + (size_t)bc * 2048;
  float yreg[8];
#pragma unroll
  for (int kk = 0; kk < 8; ++kk) {
    int t = tid + 256 * kk;
    float v = row[t];
    yreg[kk] = v;
    s[t] = make_float2(v, 0.f);
    s[2048 + t] = make_float2(0.f, 0.f);
  }
  __syncthreads();
  dif_fft<4096, false, 0>(s, tw, tid);
  const float2* kfc = kf + (size_t)c * 4096;
#pragma unroll
  for (int kk = 0; kk < 16; ++kk) {
    int m = tid + 256 * kk;
    float2 a = s[m], bv = kfc[m];
    s[m] = make_float2((a.x * bv.x - a.y * bv.y) * (1.0f / 4096.0f),
                       (a.x * bv.y + a.y * bv.x) * (1.0f / 4096.0f));
  }
  __syncthreads();
  dit_ifft<4096, 0>(s, tw, tid);
  const float Dc = D[c];
#pragma unroll
  for (int kk = 0; kk < 8; ++kk) {
    int t = tid + 256 * kk;
    float ssm = s[t].x + Dc * yreg[kk];
    row[t] = 0.5f * ssm * (1.0f + erff(ssm * 0.70710678f));  // exact GELU
  }
}

// ---------------------------------------------------------------------------
// Kernel 5: out[b,t,o] = sum_c h[b,t,c] * W[o,c] + b_out[o] + x[b,t,o]
// h stored (B,C,T). grid = B * (T/32) = 1024, block = 256, 4x4 reg tiles.
// ---------------------------------------------------------------------------
__global__ __launch_bounds__(256) void k_out(const float* __restrict__ h_tr,
                                             const float* __restrict__ W,
                                             const float* __restrict__ bout,
                                             const float* __restrict__ x,
                                             float* __restrict__ out) {
  __shared__ float wt[32 * 132];  // [cc][o], padded for alignment/banks
  __shared__ float hs[32 * 36];   // [cc][tl]
  const int tid = threadIdx.x;
  const int b = blockIdx.x >> 6;
  const int t0 = (blockIdx.x & 63) << 5;
  const int tg = tid >> 5, oo = tid & 31;
  float acc[4][4];
#pragma unroll
  for (int i = 0; i < 4; ++i)
#pragma unroll
    for (int j = 0; j < 4; ++j) acc[i][j] = 0.f;

  for (int c0 = 0; c0 < 128; c0 += 32) {
#pragma unroll
    for (int r = 0; r < 16; ++r) {
      int idx = tid + 256 * r;  // 128 o x 32 cc
      int o = idx >> 5, cc = idx & 31;
      wt[cc * 132 + o] = W[(size_t)o * 128 + c0 + cc];
    }
#pragma unroll
    for (int r = 0; r < 4; ++r) {
      int idx = tid + 256 * r;  // 32 cc x 32 tl
      int cc = idx >> 5, tl = idx & 31;
      hs[cc * 36 + tl] = h_tr[((size_t)b * 128 + c0 + cc) * 2048 + t0 + tl];
    }
    __syncthreads();
#pragma unroll 8
    for (int cc = 0; cc < 32; ++cc) {
      const float4 h4 = *(const float4*)(hs + cc * 36 + tg * 4);
      const float4 w4 = *(const float4*)(wt + cc * 132 + oo * 4);
      acc[0][0] += h4.x * w4.x; acc[0][1] += h4.x * w4.y; acc[0][2] += h4.x * w4.z; acc[0][3] += h4.x * w4.w;
      acc[1][0] += h4.y * w4.x; acc[1][1] += h4.y * w4.y; acc[1][2] += h4.y * w4.z; acc[1][3] += h4.y * w4.w;
      acc[2][0] += h4.z * w4.x; acc[2][1] += h4.z * w4.y; acc[2][2] += h4.z * w4.z; acc[2][3] += h4.z * w4.w;
      acc[3][0] += h4.w * w4.x; acc[3][1] += h4.w * w4.y; acc[3][2] += h4.w * w4.z; acc[3][3] += h4.w * w4.w;
    }
    __syncthreads();
  }
#pragma unroll
  for (int i = 0; i < 4; ++i) {
    int t = t0 + tg * 4 + i;
    size_t off = ((size_t)b * 2048 + t) * 128 + oo * 4;
    float4 xv = *(const float4*)(x + off);
    float4 bo = *(const float4*)(bout + (size_t)oo * 4);
    float4 o4;
    o4.x = acc[i][0] + bo.x + xv.x;
    o4.y = acc[i][1] + bo.y + xv.y;
    o4.z = acc[i][2] + bo.z + xv.z;
    o4.w = acc[i][3] + bo.w + xv.w;
    *(float4*)(out + off) = o4;
  }
}

// ---------------------------------------------------------------------------

extern "C" void kernel_launch(void* const* d_in, const int* in_sizes, int n_in,
                              void* d_out, int out_size, void* d_ws, size_t ws_size,
                              hipStream_t stream) {
  (void)in_sizes; (void)n_in; (void)out_size; (void)ws_size;
  const float* x  = (const float*)d_in[0];
  const float* g  = (const float*)d_in[1];
  const float* be = (const float*)d_in[2];
  const float* Lr = (const float*)d_in[3];
  const float* Li = (const float*)d_in[4];
  const float* Pr = (const float*)d_in[5];
  const float* Pi = (const float*)d_in[6];
  const float* Br = (const float*)d_in[7];
  const float* Bi = (const float*)d_in[8];
  const float* Cr = (const float*)d_in[9];
  const float* Ci = (const float*)d_in[10];
  const float* D  = (const float*)d_in[11];
  const float* W  = (const float*)d_in[12];
  const float* bo = (const float*)d_in[13];
  float* out = (float*)d_out;

  char* ws = (char*)d_ws;
  float*  y_tr = (float*)ws;                    // 16 MiB: y (B,C,T), reused in-place as h
  float2* arr  = (float2*)(ws + (16u << 20));   //  2 MiB: at_roots (C, L)
  float2* kf   = (float2*)(ws + (18u << 20));   //  4 MiB: kernel spectrum (C, 4096), bit-reversed

  hipLaunchKernelGGL(k_ln_t, dim3(1024), dim3(256), 0, stream, x, g, be, y_tr);
  hipLaunchKernelGGL(k_ar,   dim3(512),  dim3(256), 0, stream, Lr, Li, Pr, Pi, Br, Bi, Cr, Ci, arr);
  hipLaunchKernelGGL(k_kf,   dim3(128),  dim3(256), 0, stream, arr, kf);
  hipLaunchKernelGGL(k_conv, dim3(2048), dim3(256), 0, stream, y_tr, kf, D);
  hipLaunchKernelGGL(k_out,  dim3(1024), dim3(256), 0, stream, y_tr, W, bo, x, out);
}

// Round 2
// 103.902 us; speedup vs baseline: 1.5525x; 1.5525x over previous
//
#include <hip/hip_runtime.h>

// ---------------------------------------------------------------------------
// Problem constants: B=16, T=2048, C=128, N=64, FFT length NF=4096
// ---------------------------------------------------------------------------

#define SW(i) ((i) ^ (((i) >> 4) & 15))  // LDS float2-index swizzle: all FFT strides -> 4-way b64 minimum

static __device__ __forceinline__ float2 cmulf(float2 a, float2 b) {
  return make_float2(a.x * b.x - a.y * b.y, a.x * b.y + a.y * b.x);
}
static __device__ __forceinline__ float2 cadd(float2 a, float2 b) { return make_float2(a.x + b.x, a.y + b.y); }
static __device__ __forceinline__ float2 csub(float2 a, float2 b) { return make_float2(a.x - b.x, a.y - b.y); }
static __device__ __forceinline__ float2 cconj(float2 a) { return make_float2(a.x, -a.y); }

// Forward radix-4 DIF butterfly (== two radix-2 DIF stages). Twiddles w2=w1^2, w3=w1^3.
// placement: s[i]=a, s[i+Q]=b, s[i+2Q]=c, s[i+3Q]=d after call.
static __device__ __forceinline__ void bf4f(float2& a, float2& b, float2& c, float2& d, float2 w1) {
  float2 t0 = cadd(a, c), t1 = csub(a, c), t2 = cadd(b, d), t3 = csub(b, d);
  float2 w2 = cmulf(w1, w1), w3 = cmulf(w2, w1);
  float2 o0 = cadd(t0, t2);
  float2 o1 = cmulf(csub(t0, t2), w2);
  float2 o2 = cmulf(make_float2(t1.x + t3.y, t1.y - t3.x), w1);  // (t1 - i t3) w1
  float2 o3 = cmulf(make_float2(t1.x - t3.y, t1.y + t3.x), w3);  // (t1 + i t3) w3
  a = o0; b = o1; c = o2; d = o3;
}
static __device__ __forceinline__ void bf4f1(float2& a, float2& b, float2& c, float2& d) {  // w1 = 1
  float2 t0 = cadd(a, c), t1 = csub(a, c), t2 = cadd(b, d), t3 = csub(b, d);
  a = cadd(t0, t2);
  b = csub(t0, t2);
  c = make_float2(t1.x + t3.y, t1.y - t3.x);
  d = make_float2(t1.x - t3.y, t1.y + t3.x);
}
// Inverse radix-4 DIT butterfly; u1 = conj(forward twiddle), u2 = u1^2.
static __device__ __forceinline__ void bf4i(float2& a, float2& b, float2& c, float2& d, float2 u1) {
  float2 u2 = cmulf(u1, u1);
  float2 tb = cmulf(b, u2), td = cmulf(d, u2);
  float2 a1 = cadd(a, tb), b1 = csub(a, tb), c1 = cadd(c, td), d1 = csub(c, td);
  float2 tc = cmulf(c1, u1), te = cmulf(d1, u1);
  a = cadd(a1, tc);
  c = csub(a1, tc);
  b = make_float2(b1.x - te.y, b1.y + te.x);  // b1 + i te
  d = make_float2(b1.x + te.y, b1.y - te.x);  // b1 - i te
}
static __device__ __forceinline__ void bf4i1(float2& a, float2& b, float2& c, float2& d) {  // u1 = 1
  float2 a1 = cadd(a, b), b1 = csub(a, b), c1 = cadd(c, d), d1 = csub(c, d);
  a = cadd(a1, c1);
  c = csub(a1, c1);
  b = make_float2(b1.x - d1.y, b1.y + d1.x);
  d = make_float2(b1.x + d1.y, b1.y - d1.x);
}

// LDS radix-4 stages for N=4096, 256 threads, swizzled indices, quarter table tw[1024]
template <int Q>
static __device__ __forceinline__ void fwd_stage(float2* s, const float2* tw, int tid) {
  constexpr int S = 4096 / (4 * Q);
#pragma unroll
  for (int m = 0; m < 4; ++m) {
    int k = tid + 256 * m;
    int j = k & (Q - 1);
    int i = ((k - j) << 2) + j;
    float2 a = s[SW(i)], b = s[SW(i + Q)], c = s[SW(i + 2 * Q)], d = s[SW(i + 3 * Q)];
    bf4f(a, b, c, d, tw[SW(j * S)]);
    s[SW(i)] = a; s[SW(i + Q)] = b; s[SW(i + 2 * Q)] = c; s[SW(i + 3 * Q)] = d;
  }
  __syncthreads();
}
template <int Q>
static __device__ __forceinline__ void inv_stage(float2* s, const float2* tw, int tid) {
  constexpr int S = 4096 / (4 * Q);
#pragma unroll
  for (int m = 0; m < 4; ++m) {
    int k = tid + 256 * m;
    int j = k & (Q - 1);
    int i = ((k - j) << 2) + j;
    float2 a = s[SW(i)], b = s[SW(i + Q)], c = s[SW(i + 2 * Q)], d = s[SW(i + 3 * Q)];
    bf4i(a, b, c, d, cconj(tw[SW(j * S)]));
    s[SW(i)] = a; s[SW(i + Q)] = b; s[SW(i + 2 * Q)] = c; s[SW(i + 3 * Q)] = d;
  }
  __syncthreads();
}

// twiddle constants W_4096^{256,512,768} (used by register stages, span 4)
#define W256R 0.9238795325112867f
#define W256I -0.3826834323650898f
#define W512R 0.7071067811865476f
#define W512I -0.7071067811865476f
#define W768R 0.3826834323650898f
#define W768I -0.9238795325112867f

// ---------------------------------------------------------------------------
// Kernel 1: LayerNorm over channels + transpose (B,T,C) -> (B,C,T)
// ---------------------------------------------------------------------------
__global__ __launch_bounds__(256) void k_ln_t(const float* __restrict__ x,
                                              const float* __restrict__ gamma,
                                              const float* __restrict__ beta,
                                              float* __restrict__ y_tr) {
  __shared__ float tile[32 * 129];
  __shared__ float sg[128], sb[128];
  const int tid = threadIdx.x;
  const int b = blockIdx.x >> 6;
  const int t0 = (blockIdx.x & 63) << 5;
  if (tid < 128) { sg[tid] = gamma[tid]; sb[tid] = beta[tid]; }
  const float* xb = x + ((size_t)b * 2048 + t0) * 128;
#pragma unroll
  for (int r = 0; r < 16; ++r) {
    int idx = tid + 256 * r;
    tile[(idx >> 7) * 129 + (idx & 127)] = xb[idx];
  }
  __syncthreads();
  const int row = tid >> 3, sgp = tid & 7;
  float sum = 0.f, sq = 0.f;
#pragma unroll
  for (int i = 0; i < 16; ++i) {
    float v = tile[row * 129 + sgp * 16 + i];
    sum += v;
    sq += v * v;
  }
  sum += __shfl_xor(sum, 1); sq += __shfl_xor(sq, 1);
  sum += __shfl_xor(sum, 2); sq += __shfl_xor(sq, 2);
  sum += __shfl_xor(sum, 4); sq += __shfl_xor(sq, 4);
  float mean = sum * (1.0f / 128.0f);
  float var = sq * (1.0f / 128.0f) - mean * mean;
  float rstd = 1.0f / sqrtf(var + 1e-5f);
#pragma unroll
  for (int i = 0; i < 16; ++i) {
    int cc = sgp * 16 + i;
    float v = tile[row * 129 + cc];
    tile[row * 129 + cc] = (v - mean) * rstd * sg[cc] + sb[cc];
  }
  __syncthreads();
  float* yb = y_tr + (size_t)b * 128 * 2048 + t0;
#pragma unroll
  for (int r = 0; r < 16; ++r) {
    int idx = tid + 256 * r;
    int cc = idx >> 5, tl = idx & 31;
    yb[(size_t)cc * 2048 + tl] = tile[tl * 129 + cc];
  }
}

// ---------------------------------------------------------------------------
// Kernel 2: at_roots (DPLR generating function at the 2048 unity roots)
// ---------------------------------------------------------------------------
__global__ __launch_bounds__(256) void k_ar(const float* __restrict__ Lr, const float* __restrict__ Li,
                                            const float* __restrict__ Pr, const float* __restrict__ Pi,
                                            const float* __restrict__ Br, const float* __restrict__ Bi,
                                            const float* __restrict__ Cr, const float* __restrict__ Ci,
                                            float2* __restrict__ arr) {
  __shared__ float2 sLam[64], sv00[64], sv01[64], sv10[64], sv11[64];
  const int c = blockIdx.x >> 2;
  const int slab = blockIdx.x & 3;
  const int tid = threadIdx.x;
  if (tid < 64) {
    int i = c * 64 + tid;
    float lr = fminf(Lr[i], 1e-4f), li = Li[i];
    float pr = Pr[i], pi = Pi[i];
    float br = Br[i], bi = Bi[i];
    float cr = Cr[i], ci = Ci[i];
    sLam[tid] = make_float2(lr, li);
    sv00[tid] = make_float2(cr * br + ci * bi, cr * bi - ci * br);
    sv01[tid] = make_float2(cr * pr + ci * pi, cr * pi - ci * pr);
    sv10[tid] = make_float2(pr * br + pi * bi, pr * bi - pi * br);
    sv11[tid] = make_float2(pr * pr + pi * pi, 0.0f);
  }
  __syncthreads();
#pragma unroll
  for (int kk = 0; kk < 2; ++kk) {
    int l = slab * 512 + tid + 256 * kk;
    float theta = (-6.2831855f * (float)l) * (1.0f / 2048.0f);
    float om_i, om_r;
    sincosf(theta, &om_i, &om_r);
    float pr_ = 1.0f + om_r, pi_ = om_i;
    float mr_ = 1.0f - om_r, mi_ = -om_i;
    float invd = 1.0f / (pr_ * pr_ + pi_ * pi_);
    float gr = 200.0f * ((mr_ * pr_ + mi_ * pi_) * invd);
    float gi = 200.0f * ((mi_ * pr_ - mr_ * pi_) * invd);
    float c2r = 2.0f * pr_ * invd, c2i = -2.0f * pi_ * invd;
    float s00r = 0.f, s00i = 0.f, s01r = 0.f, s01i = 0.f;
    float s10r = 0.f, s10i = 0.f, s11r = 0.f, s11i = 0.f;
#pragma unroll 8
    for (int n = 0; n < 64; ++n) {
      float2 lam = sLam[n];
      float dr = gr - lam.x, di = gi - lam.y;
      float idn = 1.0f / (dr * dr + di * di);
      float ir = dr * idn, ii = -di * idn;
      float2 v;
      v = sv00[n]; s00r += v.x * ir - v.y * ii; s00i += v.x * ii + v.y * ir;
      v = sv01[n]; s01r += v.x * ir - v.y * ii; s01i += v.x * ii + v.y * ir;
      v = sv10[n]; s10r += v.x * ir - v.y * ii; s10i += v.x * ii + v.y * ir;
      v = sv11[n]; s11r += v.x * ir - v.y * ii; s11i += v.x * ii + v.y * ir;
    }
    float dr2 = 1.0f + s11r, di2 = s11i;
    float idn2 = 1.0f / (dr2 * dr2 + di2 * di2);
    float rr = dr2 * idn2, ri = -di2 * idn2;
    float t1r = s01r * rr - s01i * ri, t1i = s01r * ri + s01i * rr;
    float t2r = t1r * s10r - t1i * s10i, t2i = t1r * s10i + t1i * s10r;
    float fr = s00r - t2r, fi = s00i - t2i;
    arr[(size_t)c * 2048 + l] = make_float2(c2r * fr - c2i * fi, c2r * fi + c2i * fr);
  }
}

// ---------------------------------------------------------------------------
// Kernel 3 helpers (radix-2, used only by k_kf: 128 blocks, not hot)
// ---------------------------------------------------------------------------
static __device__ __forceinline__ void build_tw2048(float2* tw, int tid) {
  for (int j = tid; j < 2048; j += 256) {
    float sv, cv;
    sincospif(-(float)j * (1.0f / 2048.0f), &sv, &cv);
    tw[j] = make_float2(cv, sv);
  }
}
template <int NPTS, bool CONJ, int TWSHIFT>
static __device__ __forceinline__ void dif_fft(float2* s, const float2* tw, int tid) {
  int step = 1;
  for (int m = NPTS >> 1; m >= 1; m >>= 1, step <<= 1) {
    for (int k = tid; k < (NPTS >> 1); k += 256) {
      int j = k & (m - 1);
      int i0 = ((k - j) << 1) + j;
      int i1 = i0 + m;
      float2 a = s[i0], b = s[i1];
      s[i0] = make_float2(a.x + b.x, a.y + b.y);
      float2 d = make_float2(a.x - b.x, a.y - b.y);
      float2 w = tw[(j * step) << TWSHIFT];
      if (CONJ) w.y = -w.y;
      s[i1] = cmulf(d, w);
    }
    __syncthreads();
  }
}

// Kernel 3: per channel: ifft_2048(at_roots).real -> zero-pad -> fft_4096 (bit-rev order),
// pre-scaled by 1/4096 for the conv inverse.
__global__ __launch_bounds__(256) void k_kf(const float2* __restrict__ arr, float2* __restrict__ kf) {
  __shared__ float2 tw[2048];
  __shared__ float2 s[4096];
  const int tid = threadIdx.x;
  const int c = blockIdx.x;
  build_tw2048(tw, tid);
  for (int k = tid; k < 2048; k += 256) s[2048 + k] = arr[(size_t)c * 2048 + k];
  __syncthreads();
  dif_fft<2048, true, 1>(s + 2048, tw, tid);
#pragma unroll
  for (int kk = 0; kk < 8; ++kk) {
    int t = tid + 256 * kk;
    int r = (int)(__brev((unsigned)t) >> 21);
    s[t] = make_float2(s[2048 + r].x * (1.0f / 2048.0f), 0.0f);
  }
  __syncthreads();
#pragma unroll
  for (int kk = 0; kk < 8; ++kk) s[2048 + tid + 256 * kk] = make_float2(0.f, 0.f);
  __syncthreads();
  dif_fft<4096, false, 0>(s, tw, tid);
#pragma unroll
  for (int kk = 0; kk < 16; ++kk) {
    int m = tid + 256 * kk;
    kf[(size_t)c * 4096 + m] = make_float2(s[m].x * (1.0f / 4096.0f), s[m].y * (1.0f / 4096.0f));
  }
}

// ---------------------------------------------------------------------------
// Kernel 4: paired real FFT conv. Block p handles rows (b,c) and (b+8,c) packed
// as z = y1 + i*y2 (conv with the real kernel keeps them in re/im exactly).
// Radix-4, swizzled LDS, first fwd stage fused with load (upper half zero),
// spans {4,1} + spectral multiply + inverse spans {1,4} in registers.
// grid = 1024, block = 256, LDS = 40 KB -> 4 blocks/CU.
// ---------------------------------------------------------------------------
__global__ __launch_bounds__(256) void k_conv(float* __restrict__ y_tr,
                                              const float2* __restrict__ kf,
                                              const float* __restrict__ D) {
  __shared__ float2 tw[1024];
  __shared__ float2 s[4096];
  const int tid = threadIdx.x;
  const int p = blockIdx.x;
  const int b = p >> 7, c = p & 127;
  for (int j = tid; j < 1024; j += 256) {
    float sv, cv;
    sincospif(-(float)j * (1.0f / 2048.0f), &sv, &cv);
    tw[SW(j)] = make_float2(cv, sv);
  }
  float* __restrict__ r1 = y_tr + (size_t)(b * 128 + c) * 2048;
  float* __restrict__ r2 = y_tr + (size_t)((b + 8) * 128 + c) * 2048;
  __syncthreads();
  // ---- forward stage Q=1024 fused with global load; legs 2,3 are zero ----
#pragma unroll
  for (int m = 0; m < 4; ++m) {
    int k = tid + 256 * m;  // k in [0,1024)
    float2 a = make_float2(r1[k], r2[k]);
    float2 bb = make_float2(r1[k + 1024], r2[k + 1024]);
    float2 w1 = tw[SW(k)];
    float2 w2 = cmulf(w1, w1), w3 = cmulf(w2, w1);
    s[SW(k)] = cadd(a, bb);
    s[SW(k + 1024)] = cmulf(csub(a, bb), w2);
    s[SW(k + 2048)] = cmulf(make_float2(a.x + bb.y, a.y - bb.x), w1);  // (a - i b) w1
    s[SW(k + 3072)] = cmulf(make_float2(a.x - bb.y, a.y + bb.x), w3);  // (a + i b) w3
  }
  __syncthreads();
  fwd_stage<256>(s, tw, tid);
  fwd_stage<64>(s, tw, tid);
  fwd_stage<16>(s, tw, tid);
  // ---- gather 16 consecutive into registers ----
  float2 v[16];
  const int base = tid << 4;
#pragma unroll
  for (int e = 0; e < 16; ++e) v[e] = s[SW(base + e)];
  __syncthreads();  // gathers done before kf overwrites s
  // stage kf into s, coalesced
  const float2* __restrict__ kfc = kf + (size_t)c * 4096;
#pragma unroll
  for (int m = 0; m < 16; ++m) {
    int i = tid + 256 * m;
    s[SW(i)] = kfc[i];
  }
  // ---- register stages: Q=4 then Q=1 (twiddles constant) ----
  bf4f1(v[0], v[4], v[8], v[12]);
  bf4f(v[1], v[5], v[9], v[13], make_float2(W256R, W256I));
  bf4f(v[2], v[6], v[10], v[14], make_float2(W512R, W512I));
  bf4f(v[3], v[7], v[11], v[15], make_float2(W768R, W768I));
  bf4f1(v[0], v[1], v[2], v[3]);
  bf4f1(v[4], v[5], v[6], v[7]);
  bf4f1(v[8], v[9], v[10], v[11]);
  bf4f1(v[12], v[13], v[14], v[15]);
  __syncthreads();  // kf visible
  // ---- spectral multiply (kf pre-scaled by 1/4096) ----
#pragma unroll
  for (int e = 0; e < 16; ++e) v[e] = cmulf(v[e], s[SW(base + e)]);
  // ---- inverse register stages: Q=1 then Q=4 ----
  bf4i1(v[0], v[1], v[2], v[3]);
  bf4i1(v[4], v[5], v[6], v[7]);
  bf4i1(v[8], v[9], v[10], v[11]);
  bf4i1(v[12], v[13], v[14], v[15]);
  bf4i1(v[0], v[4], v[8], v[12]);
  bf4i(v[1], v[5], v[9], v[13], make_float2(W256R, -W256I));
  bf4i(v[2], v[6], v[10], v[14], make_float2(W512R, -W512I));
  bf4i(v[3], v[7], v[11], v[15], make_float2(W768R, -W768I));
  // scatter back (own range; mult also read only own range -> no barrier needed before)
#pragma unroll
  for (int e = 0; e < 16; ++e) s[SW(base + e)] = v[e];
  __syncthreads();
  inv_stage<16>(s, tw, tid);
  inv_stage<64>(s, tw, tid);
  inv_stage<256>(s, tw, tid);
  // ---- final inverse stage Q=1024 fused with D*y + GELU + store ----
  const float Dc = D[c];
#pragma unroll
  for (int m = 0; m < 4; ++m) {
    int i = tid + 256 * m;  // outputs i and i+1024 only (t < 2048)
    float2 a = s[SW(i)], bb = s[SW(i + 1024)], cc = s[SW(i + 2048)], dd = s[SW(i + 3072)];
    float2 u1 = cconj(tw[SW(i)]);
    float2 u2 = cmulf(u1, u1);
    float2 tb = cmulf(bb, u2), td = cmulf(dd, u2);
    float2 a1 = cadd(a, tb), b1 = csub(a, tb), c1 = cadd(cc, td), d1 = csub(cc, td);
    float2 tc = cmulf(c1, u1), te = cmulf(d1, u1);
    float2 o0 = cadd(a1, tc);                           // time index i
    float2 o1 = make_float2(b1.x - te.y, b1.y + te.x);  // time index i+1024
    float y1a = r1[i], y2a = r2[i], y1b = r1[i + 1024], y2b = r2[i + 1024];
    float s1 = o0.x + Dc * y1a;
    float s2 = o0.y + Dc * y2a;
    float s3 = o1.x + Dc * y1b;
    float s4 = o1.y + Dc * y2b;
    r1[i] = 0.5f * s1 * (1.0f + erff(s1 * 0.70710678f));
    r2[i] = 0.5f * s2 * (1.0f + erff(s2 * 0.70710678f));
    r1[i + 1024] = 0.5f * s3 * (1.0f + erff(s3 * 0.70710678f));
    r2[i + 1024] = 0.5f * s4 * (1.0f + erff(s4 * 0.70710678f));
  }
}

// ---------------------------------------------------------------------------
// Kernel 5: out[b,t,o] = sum_c h[b,t,c] * W[o,c] + b_out[o] + x[b,t,o]
// ---------------------------------------------------------------------------
__global__ __launch_bounds__(256) void k_out(const float* __restrict__ h_tr,
                                             const float* __restrict__ W,
                                             const float* __restrict__ bout,
                                             const float* __restrict__ x,
                                             float* __restrict__ out) {
  __shared__ float wt[32 * 132];
  __shared__ float hs[32 * 36];
  const int tid = threadIdx.x;
  const int b = blockIdx.x >> 6;
  const int t0 = (blockIdx.x & 63) << 5;
  const int tg = tid >> 5, oo = tid & 31;
  float acc[4][4];
#pragma unroll
  for (int i = 0; i < 4; ++i)
#pragma unroll
    for (int j = 0; j < 4; ++j) acc[i][j] = 0.f;

  for (int c0 = 0; c0 < 128; c0 += 32) {
#pragma unroll
    for (int r = 0; r < 16; ++r) {
      int idx = tid + 256 * r;
      int o = idx >> 5, cc = idx & 31;
      wt[cc * 132 + o] = W[(size_t)o * 128 + c0 + cc];
    }
#pragma unroll
    for (int r = 0; r < 4; ++r) {
      int idx = tid + 256 * r;
      int cc = idx >> 5, tl = idx & 31;
      hs[cc * 36 + tl] = h_tr[((size_t)b * 128 + c0 + cc) * 2048 + t0 + tl];
    }
    __syncthreads();
#pragma unroll 8
    for (int cc = 0; cc < 32; ++cc) {
      const float4 h4 = *(const float4*)(hs + cc * 36 + tg * 4);
      const float4 w4 = *(const float4*)(wt + cc * 132 + oo * 4);
      acc[0][0] += h4.x * w4.x; acc[0][1] += h4.x * w4.y; acc[0][2] += h4.x * w4.z; acc[0][3] += h4.x * w4.w;
      acc[1][0] += h4.y * w4.x; acc[1][1] += h4.y * w4.y; acc[1][2] += h4.y * w4.z; acc[1][3] += h4.y * w4.w;
      acc[2][0] += h4.z * w4.x; acc[2][1] += h4.z * w4.y; acc[2][2] += h4.z * w4.z; acc[2][3] += h4.z * w4.w;
      acc[3][0] += h4.w * w4.x; acc[3][1] += h4.w * w4.y; acc[3][2] += h4.w * w4.z; acc[3][3] += h4.w * w4.w;
    }
    __syncthreads();
  }
#pragma unroll
  for (int i = 0; i < 4; ++i) {
    int t = t0 + tg * 4 + i;
    size_t off = ((size_t)b * 2048 + t) * 128 + oo * 4;
    float4 xv = *(const float4*)(x + off);
    float4 bo = *(const float4*)(bout + (size_t)oo * 4);
    float4 o4;
    o4.x = acc[i][0] + bo.x + xv.x;
    o4.y = acc[i][1] + bo.y + xv.y;
    o4.z = acc[i][2] + bo.z + xv.z;
    o4.w = acc[i][3] + bo.w + xv.w;
    *(float4*)(out + off) = o4;
  }
}

// ---------------------------------------------------------------------------

extern "C" void kernel_launch(void* const* d_in, const int* in_sizes, int n_in,
                              void* d_out, int out_size, void* d_ws, size_t ws_size,
                              hipStream_t stream) {
  (void)in_sizes; (void)n_in; (void)out_size; (void)ws_size;
  const float* x  = (const float*)d_in[0];
  const float* g  = (const float*)d_in[1];
  const float* be = (const float*)d_in[2];
  const float* Lr = (const float*)d_in[3];
  const float* Li = (const float*)d_in[4];
  const float* Pr = (const float*)d_in[5];
  const float* Pi = (const float*)d_in[6];
  const float* Br = (const float*)d_in[7];
  const float* Bi = (const float*)d_in[8];
  const float* Cr = (const float*)d_in[9];
  const float* Ci = (const float*)d_in[10];
  const float* D  = (const float*)d_in[11];
  const float* W  = (const float*)d_in[12];
  const float* bo = (const float*)d_in[13];
  float* out = (float*)d_out;

  char* ws = (char*)d_ws;
  float*  y_tr = (float*)ws;                    // 16 MiB: y (B,C,T), reused in-place as h
  float2* arr  = (float2*)(ws + (16u << 20));   //  2 MiB: at_roots (C, L)
  float2* kf   = (float2*)(ws + (18u << 20));   //  4 MiB: kernel spectrum (C, 4096), bit-rev, /4096

  hipLaunchKernelGGL(k_ln_t, dim3(1024), dim3(256), 0, stream, x, g, be, y_tr);
  hipLaunchKernelGGL(k_ar,   dim3(512),  dim3(256), 0, stream, Lr, Li, Pr, Pi, Br, Bi, Cr, Ci, arr);
  hipLaunchKernelGGL(k_kf,   dim3(128),  dim3(256), 0, stream, arr, kf);
  hipLaunchKernelGGL(k_conv, dim3(1024), dim3(256), 0, stream, y_tr, kf, D);
  hipLaunchKernelGGL(k_out,  dim3(1024), dim3(256), 0, stream, y_tr, W, bo, x, out);
}

// Round 3
// 94.950 us; speedup vs baseline: 1.6989x; 1.0943x over previous
//
#include <hip/hip_runtime.h>

// ---------------------------------------------------------------------------
// Problem constants: B=16, T=2048, C=128, N=64, FFT length NF=4096
// ---------------------------------------------------------------------------

#define PAD(i) ((i) + ((i) >> 4))  // LDS float2 padding: 1 extra float2 per 16 -> all exchange patterns at b64 floor

static __device__ __forceinline__ float2 cmulf(float2 a, float2 b) {
  return make_float2(a.x * b.x - a.y * b.y, a.x * b.y + a.y * b.x);
}
static __device__ __forceinline__ float2 cadd(float2 a, float2 b) { return make_float2(a.x + b.x, a.y + b.y); }
static __device__ __forceinline__ float2 csub(float2 a, float2 b) { return make_float2(a.x - b.x, a.y - b.y); }
static __device__ __forceinline__ float2 cconj(float2 a) { return make_float2(a.x, -a.y); }
static __device__ __forceinline__ float gelu1(float x) { return 0.5f * x * (1.0f + erff(x * 0.70710678f)); }

// Generic radix-4 DIF butterfly. INV=false: forward (w1 = e^{-}); INV=true: inverse (w1 = e^{+}, internal i flipped).
template <bool INV>
static __device__ __forceinline__ void bf4g(float2& a, float2& b, float2& c, float2& d, float2 w1) {
  float2 t0 = cadd(a, c), t1 = csub(a, c), t2 = cadd(b, d), t3 = csub(b, d);
  float2 w2 = cmulf(w1, w1), w3 = cmulf(w2, w1);
  float2 o0 = cadd(t0, t2);
  float2 o1 = cmulf(csub(t0, t2), w2);
  float2 o2, o3;
  if (!INV) {
    o2 = cmulf(make_float2(t1.x + t3.y, t1.y - t3.x), w1);  // (t1 - i t3) w1
    o3 = cmulf(make_float2(t1.x - t3.y, t1.y + t3.x), w3);  // (t1 + i t3) w3
  } else {
    o2 = cmulf(make_float2(t1.x - t3.y, t1.y + t3.x), w1);
    o3 = cmulf(make_float2(t1.x + t3.y, t1.y - t3.x), w3);
  }
  a = o0; b = o1; c = o2; d = o3;
}
static __device__ __forceinline__ void bf4f(float2& a, float2& b, float2& c, float2& d, float2 w1) {
  bf4g<false>(a, b, c, d, w1);
}
static __device__ __forceinline__ void bf4f1(float2& a, float2& b, float2& c, float2& d) {  // fwd, w=1
  float2 t0 = cadd(a, c), t1 = csub(a, c), t2 = cadd(b, d), t3 = csub(b, d);
  a = cadd(t0, t2);
  b = csub(t0, t2);
  c = make_float2(t1.x + t3.y, t1.y - t3.x);
  d = make_float2(t1.x - t3.y, t1.y + t3.x);
}
// Forward DIF with zero c,d legs (zero-padded input)
static __device__ __forceinline__ void bf4f_z(float2 a, float2 b, float2 w1,
                                              float2& o0, float2& o1, float2& o2, float2& o3) {
  float2 w2 = cmulf(w1, w1), w3 = cmulf(w2, w1);
  o0 = cadd(a, b);
  o1 = cmulf(csub(a, b), w2);
  o2 = cmulf(make_float2(a.x + b.y, a.y - b.x), w1);  // (a - i b) w1
  o3 = cmulf(make_float2(a.x - b.y, a.y + b.x), w3);  // (a + i b) w3
}
// Generic radix-4 DIT butterfly. INV=true: inverse (u1 = e^{+}); INV=false: forward (u1 = e^{-}).
template <bool INV>
static __device__ __forceinline__ void bf4h(float2& a, float2& b, float2& c, float2& d, float2 u1) {
  float2 u2 = cmulf(u1, u1);
  float2 tb = cmulf(b, u2), td = cmulf(d, u2);
  float2 a1 = cadd(a, tb), b1 = csub(a, tb), c1 = cadd(c, td), d1 = csub(c, td);
  float2 tc = cmulf(c1, u1), te = cmulf(d1, u1);
  a = cadd(a1, tc);
  c = csub(a1, tc);
  if (INV) {
    b = make_float2(b1.x - te.y, b1.y + te.x);  // b1 + i te
    d = make_float2(b1.x + te.y, b1.y - te.x);
  } else {
    b = make_float2(b1.x + te.y, b1.y - te.x);  // b1 - i te
    d = make_float2(b1.x - te.y, b1.y + te.x);
  }
}
static __device__ __forceinline__ void bf4i(float2& a, float2& b, float2& c, float2& d, float2 u1) {
  bf4h<true>(a, b, c, d, u1);
}
static __device__ __forceinline__ void bf4i1(float2& a, float2& b, float2& c, float2& d) {  // inverse, u=1
  float2 a1 = cadd(a, b), b1 = csub(a, b), c1 = cadd(c, d), d1 = csub(c, d);
  a = cadd(a1, c1);
  c = csub(a1, c1);
  b = make_float2(b1.x - d1.y, b1.y + d1.x);
  d = make_float2(b1.x + d1.y, b1.y - d1.x);
}

// twiddle constants W_16^{1,2,3} (= W_4096^{256,512,768})
#define W256R 0.9238795325112867f
#define W256I -0.3826834323650898f
#define W512R 0.7071067811865476f
#define W512I -0.7071067811865476f
#define W768R 0.3826834323650898f
#define W768I -0.9238795325112867f

// ---------------------------------------------------------------------------
// Kernel 1: LayerNorm over channels + transpose (B,T,C) -> (B,C,T)
// ---------------------------------------------------------------------------
__global__ __launch_bounds__(256) void k_ln_t(const float* __restrict__ x,
                                              const float* __restrict__ gamma,
                                              const float* __restrict__ beta,
                                              float* __restrict__ y_tr) {
  __shared__ float tile[32 * 129];
  __shared__ float sg[128], sb[128];
  const int tid = threadIdx.x;
  const int b = blockIdx.x >> 6;
  const int t0 = (blockIdx.x & 63) << 5;
  if (tid < 128) { sg[tid] = gamma[tid]; sb[tid] = beta[tid]; }
  const float* xb = x + ((size_t)b * 2048 + t0) * 128;
#pragma unroll
  for (int r = 0; r < 16; ++r) {
    int idx = tid + 256 * r;
    tile[(idx >> 7) * 129 + (idx & 127)] = xb[idx];
  }
  __syncthreads();
  const int row = tid >> 3, sgp = tid & 7;
  float sum = 0.f, sq = 0.f;
#pragma unroll
  for (int i = 0; i < 16; ++i) {
    float v = tile[row * 129 + sgp * 16 + i];
    sum += v;
    sq += v * v;
  }
  sum += __shfl_xor(sum, 1); sq += __shfl_xor(sq, 1);
  sum += __shfl_xor(sum, 2); sq += __shfl_xor(sq, 2);
  sum += __shfl_xor(sum, 4); sq += __shfl_xor(sq, 4);
  float mean = sum * (1.0f / 128.0f);
  float var = sq * (1.0f / 128.0f) - mean * mean;
  float rstd = 1.0f / sqrtf(var + 1e-5f);
#pragma unroll
  for (int i = 0; i < 16; ++i) {
    int cc = sgp * 16 + i;
    float v = tile[row * 129 + cc];
    tile[row * 129 + cc] = (v - mean) * rstd * sg[cc] + sb[cc];
  }
  __syncthreads();
  float* yb = y_tr + (size_t)b * 128 * 2048 + t0;
#pragma unroll
  for (int r = 0; r < 16; ++r) {
    int idx = tid + 256 * r;
    int cc = idx >> 5, tl = idx & 31;
    yb[(size_t)cc * 2048 + tl] = tile[tl * 129 + cc];
  }
}

// ---------------------------------------------------------------------------
// Kernel 2: at_roots (DPLR generating function at the 2048 unity roots)
// ---------------------------------------------------------------------------
__global__ __launch_bounds__(256) void k_ar(const float* __restrict__ Lr, const float* __restrict__ Li,
                                            const float* __restrict__ Pr, const float* __restrict__ Pi,
                                            const float* __restrict__ Br, const float* __restrict__ Bi,
                                            const float* __restrict__ Cr, const float* __restrict__ Ci,
                                            float2* __restrict__ arr) {
  __shared__ float2 sLam[64], sv00[64], sv01[64], sv10[64], sv11[64];
  const int c = blockIdx.x >> 2;
  const int slab = blockIdx.x & 3;
  const int tid = threadIdx.x;
  if (tid < 64) {
    int i = c * 64 + tid;
    float lr = fminf(Lr[i], 1e-4f), li = Li[i];
    float pr = Pr[i], pi = Pi[i];
    float br = Br[i], bi = Bi[i];
    float cr = Cr[i], ci = Ci[i];
    sLam[tid] = make_float2(lr, li);
    sv00[tid] = make_float2(cr * br + ci * bi, cr * bi - ci * br);
    sv01[tid] = make_float2(cr * pr + ci * pi, cr * pi - ci * pr);
    sv10[tid] = make_float2(pr * br + pi * bi, pr * bi - pi * br);
    sv11[tid] = make_float2(pr * pr + pi * pi, 0.0f);
  }
  __syncthreads();
#pragma unroll
  for (int kk = 0; kk < 2; ++kk) {
    int l = slab * 512 + tid + 256 * kk;
    float theta = (-6.2831855f * (float)l) * (1.0f / 2048.0f);
    float om_i, om_r;
    sincosf(theta, &om_i, &om_r);
    float pr_ = 1.0f + om_r, pi_ = om_i;
    float mr_ = 1.0f - om_r, mi_ = -om_i;
    float invd = 1.0f / (pr_ * pr_ + pi_ * pi_);
    float gr = 200.0f * ((mr_ * pr_ + mi_ * pi_) * invd);
    float gi = 200.0f * ((mi_ * pr_ - mr_ * pi_) * invd);
    float c2r = 2.0f * pr_ * invd, c2i = -2.0f * pi_ * invd;
    float s00r = 0.f, s00i = 0.f, s01r = 0.f, s01i = 0.f;
    float s10r = 0.f, s10i = 0.f, s11r = 0.f, s11i = 0.f;
#pragma unroll 8
    for (int n = 0; n < 64; ++n) {
      float2 lam = sLam[n];
      float dr = gr - lam.x, di = gi - lam.y;
      float idn = 1.0f / (dr * dr + di * di);
      float ir = dr * idn, ii = -di * idn;
      float2 v;
      v = sv00[n]; s00r += v.x * ir - v.y * ii; s00i += v.x * ii + v.y * ir;
      v = sv01[n]; s01r += v.x * ir - v.y * ii; s01i += v.x * ii + v.y * ir;
      v = sv10[n]; s10r += v.x * ir - v.y * ii; s10i += v.x * ii + v.y * ir;
      v = sv11[n]; s11r += v.x * ir - v.y * ii; s11i += v.x * ii + v.y * ir;
    }
    float dr2 = 1.0f + s11r, di2 = s11i;
    float idn2 = 1.0f / (dr2 * dr2 + di2 * di2);
    float rr = dr2 * idn2, ri = -di2 * idn2;
    float t1r = s01r * rr - s01i * ri, t1i = s01r * ri + s01i * rr;
    float t2r = t1r * s10r - t1i * s10i, t2i = t1r * s10i + t1i * s10r;
    float fr = s00r - t2r, fi = s00i - t2i;
    arr[(size_t)c * 2048 + l] = make_float2(c2r * fr - c2i * fi, c2r * fi + c2i * fr);
  }
}

// ---------------------------------------------------------------------------
// Kernel 3: kf via even/odd-bin split.
//   even bins:  E[q] = (arr[q] + conj(arr[2048-q]))/2           (no FFT)
//   odd  bins:  FFT2048( real(IFFT2048(arr)) * W_4096^t )
// Stored in the 4096-DIF bit-reversed position order k_conv consumes,
// pre-scaled by 1/4096.
// ---------------------------------------------------------------------------
template <int Q, bool INV>
static __device__ __forceinline__ void kfs_dif(float2* s, int tid) {
  constexpr float SC = (float)(2048 / (4 * Q)) * (1.0f / 1024.0f);
#pragma unroll
  for (int m = 0; m < 2; ++m) {
    int k = tid + 256 * m;  // [0,512)
    int j = k & (Q - 1);
    int i = ((k - j) << 2) + j;
    float sv, cv;
    sincospif(INV ? (float)j * SC : -(float)j * SC, &sv, &cv);
    float2 w1 = make_float2(cv, sv);
    float2 a = s[PAD(i)], b = s[PAD(i + Q)], c2 = s[PAD(i + 2 * Q)], d = s[PAD(i + 3 * Q)];
    bf4g<INV>(a, b, c2, d, w1);
    s[PAD(i)] = a; s[PAD(i + Q)] = b; s[PAD(i + 2 * Q)] = c2; s[PAD(i + 3 * Q)] = d;
  }
  __syncthreads();
}
template <int Q>
static __device__ __forceinline__ void kfs_dit(float2* s, int tid) {  // forward DIT (e^{-})
  constexpr float SC = (float)(2048 / (4 * Q)) * (1.0f / 1024.0f);
#pragma unroll
  for (int m = 0; m < 2; ++m) {
    int k = tid + 256 * m;
    int j = k & (Q - 1);
    int i = ((k - j) << 2) + j;
    float sv, cv;
    sincospif(-(float)j * SC, &sv, &cv);
    float2 u1 = make_float2(cv, sv);
    float2 a = s[PAD(i)], b = s[PAD(i + Q)], c2 = s[PAD(i + 2 * Q)], d = s[PAD(i + 3 * Q)];
    bf4h<false>(a, b, c2, d, u1);
    s[PAD(i)] = a; s[PAD(i + Q)] = b; s[PAD(i + 2 * Q)] = c2; s[PAD(i + 3 * Q)] = d;
  }
  __syncthreads();
}
static __device__ __forceinline__ void kfs_r2(float2* s, int tid) {  // span-1 radix-2 (w=1, dir-agnostic)
#pragma unroll
  for (int m = 0; m < 4; ++m) {
    int k = tid + 256 * m;  // [0,1024)
    int i = 2 * k;
    float2 a = s[PAD(i)], b = s[PAD(i + 1)];
    s[PAD(i)] = cadd(a, b);
    s[PAD(i + 1)] = csub(a, b);
  }
  __syncthreads();
}

__global__ __launch_bounds__(256) void k_kf(const float2* __restrict__ arr, float2* __restrict__ kf) {
  __shared__ float2 s[2176];
  const int tid = threadIdx.x;
  const int c = blockIdx.x;
  const float2* __restrict__ ac = arr + (size_t)c * 2048;
  float2* __restrict__ kfc = kf + (size_t)c * 4096;
#pragma unroll
  for (int m = 0; m < 8; ++m) {
    int q = tid + 256 * m;
    float2 aq = ac[q];
    s[PAD(q)] = aq;
    float2 am = ac[(2048 - q) & 2047];
    kfc[__brev((unsigned)q) >> 21] =
        make_float2((aq.x + am.x) * (0.5f / 4096.0f), (aq.y - am.y) * (0.5f / 4096.0f));
  }
  __syncthreads();
  // IFFT2048 (conj DIF, bitrev11 positions out)
  kfs_dif<512, true>(s, tid);
  kfs_dif<128, true>(s, tid);
  kfs_dif<32, true>(s, tid);
  kfs_dif<8, true>(s, tid);
  kfs_dif<2, true>(s, tid);
  kfs_r2(s, tid);
  // modulate in bitrev domain: m[t] = real(k)/2048 * W_4096^t * (1/4096)
#pragma unroll
  for (int m = 0; m < 8; ++m) {
    int p = tid + 256 * m;
    int t = (int)(__brev((unsigned)p) >> 21);
    float sv, cv;
    sincospif((float)t * (1.0f / 2048.0f), &sv, &cv);
    float kr = s[PAD(p)].x * (1.0f / 8388608.0f);
    s[PAD(p)] = make_float2(kr * cv, -kr * sv);
  }
  __syncthreads();
  // FFT2048 forward DIT (bitrev in -> natural out)
  kfs_r2(s, tid);
  kfs_dit<2>(s, tid);
  kfs_dit<8>(s, tid);
  kfs_dit<32>(s, tid);
  kfs_dit<128>(s, tid);
  kfs_dit<512>(s, tid);
  // odd bins: kf[2048 + bitrev11(q)] = O[q]
#pragma unroll
  for (int m = 0; m < 8; ++m) {
    int q = tid + 256 * m;
    kfc[2048 + (int)(__brev((unsigned)q) >> 21)] = s[PAD(q)];
  }
}

// ---------------------------------------------------------------------------
// Kernel 4: paired real FFT conv, 3-level register FFT (4096 = 16*16*16).
// Block p: rows (b,c),(b+8,c) packed z = y1 + i*y2. 16 elems/thread.
// Phase A: positions t+256e (Q=1024 zero-padded, Q=256) | exchange |
// Phase B: positions 256a+16e+b (Q=64, Q=16)            | exchange |
// Phase C: positions 16u+e (Q=4, Q=1) -> multiply kf (direct global) -> mirror back.
// 4 barriers total; y kept in registers; GELU fused into final stage.
// ---------------------------------------------------------------------------
__global__ __launch_bounds__(256) void k_conv(float* __restrict__ y_tr,
                                              const float2* __restrict__ kf,
                                              const float* __restrict__ D) {
  __shared__ float2 s[4352];
  const int tid = threadIdx.x;
  const int p = blockIdx.x;
  const int b = p >> 7, c = p & 127;
  float* __restrict__ r1 = y_tr + (size_t)(b * 128 + c) * 2048;
  float* __restrict__ r2 = y_tr + (size_t)((b + 8) * 128 + c) * 2048;

  const float2 K1 = make_float2(W256R, W256I);
  const float2 K2 = make_float2(W512R, W512I);
  const float2 K3 = make_float2(W768R, W768I);

  float2 yv[8], v[16];
#pragma unroll
  for (int e = 0; e < 8; ++e) yv[e] = make_float2(r1[tid + 256 * e], r2[tid + 256 * e]);

  float sv, cv;
  // ---- forward phase A: Q=1024 (legs 2,3 zero), Q=256 ----
  sincospif(-(float)tid * (1.0f / 2048.0f), &sv, &cv);
  {
    const float2 wt = make_float2(cv, sv);  // W_4096^t
    bf4f_z(yv[0], yv[4], wt,            v[0], v[4], v[8], v[12]);
    bf4f_z(yv[1], yv[5], cmulf(wt, K1), v[1], v[5], v[9], v[13]);
    bf4f_z(yv[2], yv[6], cmulf(wt, K2), v[2], v[6], v[10], v[14]);
    bf4f_z(yv[3], yv[7], cmulf(wt, K3), v[3], v[7], v[11], v[15]);
  }
  sincospif(-(float)tid * (1.0f / 512.0f), &sv, &cv);
  {
    const float2 wq = make_float2(cv, sv);  // W_1024^t
    bf4f(v[0], v[1], v[2], v[3], wq);
    bf4f(v[4], v[5], v[6], v[7], wq);
    bf4f(v[8], v[9], v[10], v[11], wq);
    bf4f(v[12], v[13], v[14], v[15], wq);
  }
  // ---- exchange 1: write A-pattern, read B-pattern ----
  {
    const int wb0 = tid + (tid >> 4);
#pragma unroll
    for (int e = 0; e < 16; ++e) s[272 * e + wb0] = v[e];
  }
  __syncthreads();
  const int a_ = tid >> 4, b_ = tid & 15;
  const int rbB = 272 * a_ + b_;
#pragma unroll
  for (int e = 0; e < 16; ++e) v[e] = s[rbB + 17 * e];
  // ---- forward phase B: Q=64, Q=16 ----
  sincospif(-(float)b_ * (1.0f / 128.0f), &sv, &cv);
  {
    const float2 wb = make_float2(cv, sv);  // W_256^b
    bf4f(v[0], v[4], v[8], v[12], wb);
    bf4f(v[1], v[5], v[9], v[13], cmulf(wb, K1));
    bf4f(v[2], v[6], v[10], v[14], cmulf(wb, K2));
    bf4f(v[3], v[7], v[11], v[15], cmulf(wb, K3));
  }
  sincospif(-(float)b_ * (1.0f / 32.0f), &sv, &cv);
  {
    const float2 w16 = make_float2(cv, sv);  // W_64^b
    bf4f(v[0], v[1], v[2], v[3], w16);
    bf4f(v[4], v[5], v[6], v[7], w16);
    bf4f(v[8], v[9], v[10], v[11], w16);
    bf4f(v[12], v[13], v[14], v[15], w16);
  }
  // ---- exchange 2: write B-pattern (own addrs), read C-pattern ----
#pragma unroll
  for (int e = 0; e < 16; ++e) s[rbB + 17 * e] = v[e];
  __syncthreads();
#pragma unroll
  for (int e = 0; e < 16; ++e) v[e] = s[17 * tid + e];
  // ---- forward phase C: Q=4, Q=1 ----
  bf4f1(v[0], v[4], v[8], v[12]);
  bf4f(v[1], v[5], v[9], v[13], K1);
  bf4f(v[2], v[6], v[10], v[14], K2);
  bf4f(v[3], v[7], v[11], v[15], K3);
  bf4f1(v[0], v[1], v[2], v[3]);
  bf4f1(v[4], v[5], v[6], v[7]);
  bf4f1(v[8], v[9], v[10], v[11]);
  bf4f1(v[12], v[13], v[14], v[15]);
  // ---- spectral multiply: kf read directly from global (consecutive) ----
  {
    const float2* __restrict__ kfc = kf + (size_t)c * 4096 + 16 * tid;
#pragma unroll
    for (int e = 0; e < 16; ++e) v[e] = cmulf(v[e], kfc[e]);
  }
  // ---- inverse phase C: Q=1, Q=4 ----
  bf4i1(v[0], v[1], v[2], v[3]);
  bf4i1(v[4], v[5], v[6], v[7]);
  bf4i1(v[8], v[9], v[10], v[11]);
  bf4i1(v[12], v[13], v[14], v[15]);
  bf4i1(v[0], v[4], v[8], v[12]);
  bf4i(v[1], v[5], v[9], v[13], cconj(K1));
  bf4i(v[2], v[6], v[10], v[14], cconj(K2));
  bf4i(v[3], v[7], v[11], v[15], cconj(K3));
  // ---- exchange 3: write C (own addrs), read B ----
#pragma unroll
  for (int e = 0; e < 16; ++e) s[17 * tid + e] = v[e];
  __syncthreads();
#pragma unroll
  for (int e = 0; e < 16; ++e) v[e] = s[rbB + 17 * e];
  // ---- inverse phase B: Q=16, Q=64 ----
  sincospif((float)b_ * (1.0f / 32.0f), &sv, &cv);
  {
    const float2 w16c = make_float2(cv, sv);
    bf4i(v[0], v[1], v[2], v[3], w16c);
    bf4i(v[4], v[5], v[6], v[7], w16c);
    bf4i(v[8], v[9], v[10], v[11], w16c);
    bf4i(v[12], v[13], v[14], v[15], w16c);
  }
  sincospif((float)b_ * (1.0f / 128.0f), &sv, &cv);
  {
    const float2 wbc = make_float2(cv, sv);
    bf4i(v[0], v[4], v[8], v[12], wbc);
    bf4i(v[1], v[5], v[9], v[13], cmulf(wbc, cconj(K1)));
    bf4i(v[2], v[6], v[10], v[14], cmulf(wbc, cconj(K2)));
    bf4i(v[3], v[7], v[11], v[15], cmulf(wbc, cconj(K3)));
  }
  // ---- exchange 4: write B (own addrs), read A ----
#pragma unroll
  for (int e = 0; e < 16; ++e) s[rbB + 17 * e] = v[e];
  __syncthreads();
  {
    const int wb0 = tid + (tid >> 4);
#pragma unroll
    for (int e = 0; e < 16; ++e) v[e] = s[272 * e + wb0];
  }
  // ---- inverse phase A: Q=256, then Q=1024 fused with D*y + GELU + store ----
  sincospif((float)tid * (1.0f / 512.0f), &sv, &cv);
  {
    const float2 wqc = make_float2(cv, sv);
    bf4i(v[0], v[1], v[2], v[3], wqc);
    bf4i(v[4], v[5], v[6], v[7], wqc);
    bf4i(v[8], v[9], v[10], v[11], wqc);
    bf4i(v[12], v[13], v[14], v[15], wqc);
  }
  sincospif((float)tid * (1.0f / 2048.0f), &sv, &cv);
  const float2 wtc = make_float2(cv, sv);  // conj(W_4096^t)
  const float Dc = D[c];
  auto fin = [&](float2 va, float2 vb, float2 vc2, float2 vd, float2 u1, float2 ya, float2 yb2, int e0) {
    float2 u2 = cmulf(u1, u1);
    float2 tb = cmulf(vb, u2), td = cmulf(vd, u2);
    float2 a1 = cadd(va, tb), b1 = csub(va, tb), c1 = cadd(vc2, td), d1 = csub(vc2, td);
    float2 tc = cmulf(c1, u1), te = cmulf(d1, u1);
    float2 oa = cadd(a1, tc);                           // time t+256*e0
    float2 ob = make_float2(b1.x - te.y, b1.y + te.x);  // time t+256*e0+1024
    int i0 = tid + 256 * e0;
    float s1 = oa.x + Dc * ya.x;
    float s2 = oa.y + Dc * ya.y;
    float s3 = ob.x + Dc * yb2.x;
    float s4 = ob.y + Dc * yb2.y;
    r1[i0] = gelu1(s1);
    r2[i0] = gelu1(s2);
    r1[i0 + 1024] = gelu1(s3);
    r2[i0 + 1024] = gelu1(s4);
  };
  fin(v[0], v[4], v[8], v[12], wtc, yv[0], yv[4], 0);
  fin(v[1], v[5], v[9], v[13], cmulf(wtc, cconj(K1)), yv[1], yv[5], 1);
  fin(v[2], v[6], v[10], v[14], cmulf(wtc, cconj(K2)), yv[2], yv[6], 2);
  fin(v[3], v[7], v[11], v[15], cmulf(wtc, cconj(K3)), yv[3], yv[7], 3);
}

// ---------------------------------------------------------------------------
// Kernel 5: out[b,t,o] = sum_c h[b,t,c] * W[o,c] + b_out[o] + x[b,t,o]
// ---------------------------------------------------------------------------
__global__ __launch_bounds__(256) void k_out(const float* __restrict__ h_tr,
                                             const float* __restrict__ W,
                                             const float* __restrict__ bout,
                                             const float* __restrict__ x,
                                             float* __restrict__ out) {
  __shared__ float wt[32 * 132];
  __shared__ float hs[32 * 36];
  const int tid = threadIdx.x;
  const int b = blockIdx.x >> 6;
  const int t0 = (blockIdx.x & 63) << 5;
  const int tg = tid >> 5, oo = tid & 31;
  float acc[4][4];
#pragma unroll
  for (int i = 0; i < 4; ++i)
#pragma unroll
    for (int j = 0; j < 4; ++j) acc[i][j] = 0.f;

  for (int c0 = 0; c0 < 128; c0 += 32) {
#pragma unroll
    for (int r = 0; r < 16; ++r) {
      int idx = tid + 256 * r;
      int o = idx >> 5, cc = idx & 31;
      wt[cc * 132 + o] = W[(size_t)o * 128 + c0 + cc];
    }
#pragma unroll
    for (int r = 0; r < 4; ++r) {
      int idx = tid + 256 * r;
      int cc = idx >> 5, tl = idx & 31;
      hs[cc * 36 + tl] = h_tr[((size_t)b * 128 + c0 + cc) * 2048 + t0 + tl];
    }
    __syncthreads();
#pragma unroll 8
    for (int cc = 0; cc < 32; ++cc) {
      const float4 h4 = *(const float4*)(hs + cc * 36 + tg * 4);
      const float4 w4 = *(const float4*)(wt + cc * 132 + oo * 4);
      acc[0][0] += h4.x * w4.x; acc[0][1] += h4.x * w4.y; acc[0][2] += h4.x * w4.z; acc[0][3] += h4.x * w4.w;
      acc[1][0] += h4.y * w4.x; acc[1][1] += h4.y * w4.y; acc[1][2] += h4.y * w4.z; acc[1][3] += h4.y * w4.w;
      acc[2][0] += h4.z * w4.x; acc[2][1] += h4.z * w4.y; acc[2][2] += h4.z * w4.z; acc[2][3] += h4.z * w4.w;
      acc[3][0] += h4.w * w4.x; acc[3][1] += h4.w * w4.y; acc[3][2] += h4.w * w4.z; acc[3][3] += h4.w * w4.w;
    }
    __syncthreads();
  }
#pragma unroll
  for (int i = 0; i < 4; ++i) {
    int t = t0 + tg * 4 + i;
    size_t off = ((size_t)b * 2048 + t) * 128 + oo * 4;
    float4 xv = *(const float4*)(x + off);
    float4 bo = *(const float4*)(bout + (size_t)oo * 4);
    float4 o4;
    o4.x = acc[i][0] + bo.x + xv.x;
    o4.y = acc[i][1] + bo.y + xv.y;
    o4.z = acc[i][2] + bo.z + xv.z;
    o4.w = acc[i][3] + bo.w + xv.w;
    *(float4*)(out + off) = o4;
  }
}

// ---------------------------------------------------------------------------

extern "C" void kernel_launch(void* const* d_in, const int* in_sizes, int n_in,
                              void* d_out, int out_size, void* d_ws, size_t ws_size,
                              hipStream_t stream) {
  (void)in_sizes; (void)n_in; (void)out_size; (void)ws_size;
  const float* x  = (const float*)d_in[0];
  const float* g  = (const float*)d_in[1];
  const float* be = (const float*)d_in[2];
  const float* Lr = (const float*)d_in[3];
  const float* Li = (const float*)d_in[4];
  const float* Pr = (const float*)d_in[5];
  const float* Pi = (const float*)d_in[6];
  const float* Br = (const float*)d_in[7];
  const float* Bi = (const float*)d_in[8];
  const float* Cr = (const float*)d_in[9];
  const float* Ci = (const float*)d_in[10];
  const float* D  = (const float*)d_in[11];
  const float* W  = (const float*)d_in[12];
  const float* bo = (const float*)d_in[13];
  float* out = (float*)d_out;

  char* ws = (char*)d_ws;
  float*  y_tr = (float*)ws;                    // 16 MiB: y (B,C,T), reused in-place as h
  float2* arr  = (float2*)(ws + (16u << 20));   //  2 MiB: at_roots (C, L)
  float2* kf   = (float2*)(ws + (18u << 20));   //  4 MiB: kernel spectrum (C, 4096), bit-rev, /4096

  hipLaunchKernelGGL(k_ln_t, dim3(1024), dim3(256), 0, stream, x, g, be, y_tr);
  hipLaunchKernelGGL(k_ar,   dim3(512),  dim3(256), 0, stream, Lr, Li, Pr, Pi, Br, Bi, Cr, Ci, arr);
  hipLaunchKernelGGL(k_kf,   dim3(128),  dim3(256), 0, stream, arr, kf);
  hipLaunchKernelGGL(k_conv, dim3(1024), dim3(256), 0, stream, y_tr, kf, D);
  hipLaunchKernelGGL(k_out,  dim3(1024), dim3(256), 0, stream, y_tr, W, bo, x, out);
}

// Round 5
// 86.098 us; speedup vs baseline: 1.8735x; 1.1028x over previous
//
#include <hip/hip_runtime.h>

// ---------------------------------------------------------------------------
// Problem constants: B=16, T=2048, C=128, N=64, FFT length NF=4096
// ---------------------------------------------------------------------------

#define PAD(i) ((i) + ((i) >> 4))

using bf16x8 = __attribute__((ext_vector_type(8))) short;
using f32x4 = __attribute__((ext_vector_type(4))) float;
typedef unsigned short ushort_t;

static __device__ __forceinline__ float2 cmulf(float2 a, float2 b) {
  return make_float2(a.x * b.x - a.y * b.y, a.x * b.y + a.y * b.x);
}
static __device__ __forceinline__ float2 cadd(float2 a, float2 b) { return make_float2(a.x + b.x, a.y + b.y); }
static __device__ __forceinline__ float2 csub(float2 a, float2 b) { return make_float2(a.x - b.x, a.y - b.y); }
static __device__ __forceinline__ float2 cconj(float2 a) { return make_float2(a.x, -a.y); }
static __device__ __forceinline__ float gelu1(float x) { return 0.5f * x * (1.0f + erff(x * 0.70710678f)); }
static __device__ __forceinline__ ushort_t f2bf(float f) {  // RNE f32->bf16
  unsigned int u = __float_as_uint(f);
  u += 0x7FFFu + ((u >> 16) & 1u);
  return (ushort_t)(u >> 16);
}

template <bool INV>
static __device__ __forceinline__ void bf4g(float2& a, float2& b, float2& c, float2& d, float2 w1) {
  float2 t0 = cadd(a, c), t1 = csub(a, c), t2 = cadd(b, d), t3 = csub(b, d);
  float2 w2 = cmulf(w1, w1), w3 = cmulf(w2, w1);
  float2 o0 = cadd(t0, t2);
  float2 o1 = cmulf(csub(t0, t2), w2);
  float2 o2, o3;
  if (!INV) {
    o2 = cmulf(make_float2(t1.x + t3.y, t1.y - t3.x), w1);
    o3 = cmulf(make_float2(t1.x - t3.y, t1.y + t3.x), w3);
  } else {
    o2 = cmulf(make_float2(t1.x - t3.y, t1.y + t3.x), w1);
    o3 = cmulf(make_float2(t1.x + t3.y, t1.y - t3.x), w3);
  }
  a = o0; b = o1; c = o2; d = o3;
}
static __device__ __forceinline__ void bf4f(float2& a, float2& b, float2& c, float2& d, float2 w1) {
  bf4g<false>(a, b, c, d, w1);
}
static __device__ __forceinline__ void bf4f1(float2& a, float2& b, float2& c, float2& d) {
  float2 t0 = cadd(a, c), t1 = csub(a, c), t2 = cadd(b, d), t3 = csub(b, d);
  a = cadd(t0, t2);
  b = csub(t0, t2);
  c = make_float2(t1.x + t3.y, t1.y - t3.x);
  d = make_float2(t1.x - t3.y, t1.y + t3.x);
}
static __device__ __forceinline__ void bf4f_z(float2 a, float2 b, float2 w1,
                                              float2& o0, float2& o1, float2& o2, float2& o3) {
  float2 w2 = cmulf(w1, w1), w3 = cmulf(w2, w1);
  o0 = cadd(a, b);
  o1 = cmulf(csub(a, b), w2);
  o2 = cmulf(make_float2(a.x + b.y, a.y - b.x), w1);
  o3 = cmulf(make_float2(a.x - b.y, a.y + b.x), w3);
}
template <bool INV>
static __device__ __forceinline__ void bf4h(float2& a, float2& b, float2& c, float2& d, float2 u1) {
  float2 u2 = cmulf(u1, u1);
  float2 tb = cmulf(b, u2), td = cmulf(d, u2);
  float2 a1 = cadd(a, tb), b1 = csub(a, tb), c1 = cadd(c, td), d1 = csub(c, td);
  float2 tc = cmulf(c1, u1), te = cmulf(d1, u1);
  a = cadd(a1, tc);
  c = csub(a1, tc);
  if (INV) {
    b = make_float2(b1.x - te.y, b1.y + te.x);
    d = make_float2(b1.x + te.y, b1.y - te.x);
  } else {
    b = make_float2(b1.x + te.y, b1.y - te.x);
    d = make_float2(b1.x - te.y, b1.y + te.x);
  }
}
static __device__ __forceinline__ void bf4i(float2& a, float2& b, float2& c, float2& d, float2 u1) {
  bf4h<true>(a, b, c, d, u1);
}
static __device__ __forceinline__ void bf4i1(float2& a, float2& b, float2& c, float2& d) {
  float2 a1 = cadd(a, b), b1 = csub(a, b), c1 = cadd(c, d), d1 = csub(c, d);
  a = cadd(a1, c1);
  c = csub(a1, c1);
  b = make_float2(b1.x - d1.y, b1.y + d1.x);
  d = make_float2(b1.x + d1.y, b1.y - d1.x);
}

#define W256R 0.9238795325112867f
#define W256I -0.3826834323650898f
#define W512R 0.7071067811865476f
#define W512I -0.7071067811865476f
#define W768R 0.3826834323650898f
#define W768I -0.9238795325112867f

// ---------------------------------------------------------------------------
// Kernel 1: LayerNorm over channels + transpose (B,T,C) -> (B,C,T), float4 I/O
// ---------------------------------------------------------------------------
__global__ __launch_bounds__(256) void k_ln_t(const float* __restrict__ x,
                                              const float* __restrict__ gamma,
                                              const float* __restrict__ beta,
                                              float* __restrict__ y_tr) {
  __shared__ float tile[32 * 129];
  __shared__ float sg[128], sb[128];
  const int tid = threadIdx.x;
  const int b = blockIdx.x >> 6;
  const int t0 = (blockIdx.x & 63) << 5;
  if (tid < 128) { sg[tid] = gamma[tid]; sb[tid] = beta[tid]; }
  const float4* __restrict__ xb4 = (const float4*)(x + ((size_t)b * 2048 + t0) * 128);
#pragma unroll
  for (int r = 0; r < 4; ++r) {
    int idx = tid + 256 * r;  // 32 t x 32 j
    int t = idx >> 5, j = idx & 31;
    float4 v4 = xb4[idx];
    float* dst = &tile[t * 129 + 4 * j];
    dst[0] = v4.x; dst[1] = v4.y; dst[2] = v4.z; dst[3] = v4.w;
  }
  __syncthreads();
  const int row = tid >> 3, sgp = tid & 7;
  float sum = 0.f, sq = 0.f;
#pragma unroll
  for (int i = 0; i < 16; ++i) {
    float v = tile[row * 129 + sgp * 16 + i];
    sum += v;
    sq += v * v;
  }
  sum += __shfl_xor(sum, 1); sq += __shfl_xor(sq, 1);
  sum += __shfl_xor(sum, 2); sq += __shfl_xor(sq, 2);
  sum += __shfl_xor(sum, 4); sq += __shfl_xor(sq, 4);
  float mean = sum * (1.0f / 128.0f);
  float var = sq * (1.0f / 128.0f) - mean * mean;
  float rstd = 1.0f / sqrtf(var + 1e-5f);
#pragma unroll
  for (int i = 0; i < 16; ++i) {
    int cc = sgp * 16 + i;
    float v = tile[row * 129 + cc];
    tile[row * 129 + cc] = (v - mean) * rstd * sg[cc] + sb[cc];
  }
  __syncthreads();
  float* __restrict__ yb = y_tr + (size_t)b * 128 * 2048 + t0;
#pragma unroll
  for (int r = 0; r < 4; ++r) {
    int idx = tid + 256 * r;  // 128 cc x 8 tl4
    int cc = idx >> 3, tl4 = (idx & 7) * 4;
    float4 o4 = make_float4(tile[(tl4 + 0) * 129 + cc], tile[(tl4 + 1) * 129 + cc],
                            tile[(tl4 + 2) * 129 + cc], tile[(tl4 + 3) * 129 + cc]);
    *(float4*)(yb + (size_t)cc * 2048 + tl4) = o4;
  }
}

// ---------------------------------------------------------------------------
// Kernel 2: at_roots. NOTE: Omega must use the APPROXIMATE angle (sincosf of
// theta=-2pi*l/2048) exactly like the JAX reference; an exact sincospif gives
// 1+Omega == 0 at l=1024 -> inf/NaN (round-4 failure).
// ---------------------------------------------------------------------------
__global__ __launch_bounds__(256) void k_ar(const float* __restrict__ Lr, const float* __restrict__ Li,
                                            const float* __restrict__ Pr, const float* __restrict__ Pi,
                                            const float* __restrict__ Br, const float* __restrict__ Bi,
                                            const float* __restrict__ Cr, const float* __restrict__ Ci,
                                            float2* __restrict__ arr) {
  __shared__ float2 sLam[64], sv00[64], sv01[64], sv10[64], sv11[64];
  const int c = blockIdx.x >> 2;
  const int slab = blockIdx.x & 3;
  const int tid = threadIdx.x;
  if (tid < 64) {
    int i = c * 64 + tid;
    float lr = fminf(Lr[i], 1e-4f), li = Li[i];
    float pr = Pr[i], pi = Pi[i];
    float br = Br[i], bi = Bi[i];
    float cr = Cr[i], ci = Ci[i];
    sLam[tid] = make_float2(lr, li);
    sv00[tid] = make_float2(cr * br + ci * bi, cr * bi - ci * br);
    sv01[tid] = make_float2(cr * pr + ci * pi, cr * pi - ci * pr);
    sv10[tid] = make_float2(pr * br + pi * bi, pr * bi - pi * br);
    sv11[tid] = make_float2(pr * pr + pi * pi, 0.0f);
  }
  __syncthreads();
#pragma unroll
  for (int kk = 0; kk < 2; ++kk) {
    int l = slab * 512 + tid + 256 * kk;
    float theta = (-6.2831855f * (float)l) * (1.0f / 2048.0f);
    float om_i, om_r;
    sincosf(theta, &om_i, &om_r);
    float pr_ = 1.0f + om_r, pi_ = om_i;
    float mr_ = 1.0f - om_r, mi_ = -om_i;
    float invd = 1.0f / (pr_ * pr_ + pi_ * pi_);
    float gr = 200.0f * ((mr_ * pr_ + mi_ * pi_) * invd);
    float gi = 200.0f * ((mi_ * pr_ - mr_ * pi_) * invd);
    float c2r = 2.0f * pr_ * invd, c2i = -2.0f * pi_ * invd;
    float s00r = 0.f, s00i = 0.f, s01r = 0.f, s01i = 0.f;
    float s10r = 0.f, s10i = 0.f, s11r = 0.f, s11i = 0.f;
#pragma unroll 8
    for (int n = 0; n < 64; ++n) {
      float2 lam = sLam[n];
      float dr = gr - lam.x, di = gi - lam.y;
      float idn = 1.0f / (dr * dr + di * di);
      float ir = dr * idn, ii = -di * idn;
      float2 v;
      v = sv00[n]; s00r += v.x * ir - v.y * ii; s00i += v.x * ii + v.y * ir;
      v = sv01[n]; s01r += v.x * ir - v.y * ii; s01i += v.x * ii + v.y * ir;
      v = sv10[n]; s10r += v.x * ir - v.y * ii; s10i += v.x * ii + v.y * ir;
      v = sv11[n]; s11r += v.x * ir - v.y * ii; s11i += v.x * ii + v.y * ir;
    }
    float dr2 = 1.0f + s11r, di2 = s11i;
    float idn2 = 1.0f / (dr2 * dr2 + di2 * di2);
    float rr = dr2 * idn2, ri = -di2 * idn2;
    float t1r = s01r * rr - s01i * ri, t1i = s01r * ri + s01i * rr;
    float t2r = t1r * s10r - t1i * s10i, t2i = t1r * s10i + t1i * s10r;
    float fr = s00r - t2r, fi = s00i - t2i;
    arr[(size_t)c * 2048 + l] = make_float2(c2r * fr - c2i * fi, c2r * fi + c2i * fr);
  }
}

// ---------------------------------------------------------------------------
// Kernel 3: kf via even/odd-bin split (even: reflection identity; odd: 2048 FFTs)
// ---------------------------------------------------------------------------
template <int Q, bool INV>
static __device__ __forceinline__ void kfs_dif(float2* s, int tid) {
  constexpr float SC = (float)(2048 / (4 * Q)) * (1.0f / 1024.0f);
#pragma unroll
  for (int m = 0; m < 2; ++m) {
    int k = tid + 256 * m;
    int j = k & (Q - 1);
    int i = ((k - j) << 2) + j;
    float sv, cv;
    sincospif(INV ? (float)j * SC : -(float)j * SC, &sv, &cv);
    float2 w1 = make_float2(cv, sv);
    float2 a = s[PAD(i)], b = s[PAD(i + Q)], c2 = s[PAD(i + 2 * Q)], d = s[PAD(i + 3 * Q)];
    bf4g<INV>(a, b, c2, d, w1);
    s[PAD(i)] = a; s[PAD(i + Q)] = b; s[PAD(i + 2 * Q)] = c2; s[PAD(i + 3 * Q)] = d;
  }
  __syncthreads();
}
template <int Q>
static __device__ __forceinline__ void kfs_dit(float2* s, int tid) {
  constexpr float SC = (float)(2048 / (4 * Q)) * (1.0f / 1024.0f);
#pragma unroll
  for (int m = 0; m < 2; ++m) {
    int k = tid + 256 * m;
    int j = k & (Q - 1);
    int i = ((k - j) << 2) + j;
    float sv, cv;
    sincospif(-(float)j * SC, &sv, &cv);
    float2 u1 = make_float2(cv, sv);
    float2 a = s[PAD(i)], b = s[PAD(i + Q)], c2 = s[PAD(i + 2 * Q)], d = s[PAD(i + 3 * Q)];
    bf4h<false>(a, b, c2, d, u1);
    s[PAD(i)] = a; s[PAD(i + Q)] = b; s[PAD(i + 2 * Q)] = c2; s[PAD(i + 3 * Q)] = d;
  }
  __syncthreads();
}
static __device__ __forceinline__ void kfs_r2(float2* s, int tid) {
#pragma unroll
  for (int m = 0; m < 4; ++m) {
    int k = tid + 256 * m;
    int i = 2 * k;
    float2 a = s[PAD(i)], b = s[PAD(i + 1)];
    s[PAD(i)] = cadd(a, b);
    s[PAD(i + 1)] = csub(a, b);
  }
  __syncthreads();
}

__global__ __launch_bounds__(256) void k_kf(const float2* __restrict__ arr, float2* __restrict__ kf) {
  __shared__ float2 s[2176];
  const int tid = threadIdx.x;
  const int c = blockIdx.x;
  const float2* __restrict__ ac = arr + (size_t)c * 2048;
  float2* __restrict__ kfc = kf + (size_t)c * 4096;
#pragma unroll
  for (int m = 0; m < 8; ++m) {
    int q = tid + 256 * m;
    float2 aq = ac[q];
    s[PAD(q)] = aq;
    float2 am = ac[(2048 - q) & 2047];
    kfc[__brev((unsigned)q) >> 21] =
        make_float2((aq.x + am.x) * (0.5f / 4096.0f), (aq.y - am.y) * (0.5f / 4096.0f));
  }
  __syncthreads();
  kfs_dif<512, true>(s, tid);
  kfs_dif<128, true>(s, tid);
  kfs_dif<32, true>(s, tid);
  kfs_dif<8, true>(s, tid);
  kfs_dif<2, true>(s, tid);
  kfs_r2(s, tid);
#pragma unroll
  for (int m = 0; m < 8; ++m) {
    int p = tid + 256 * m;
    int t = (int)(__brev((unsigned)p) >> 21);
    float sv, cv;
    sincospif((float)t * (1.0f / 2048.0f), &sv, &cv);
    float kr = s[PAD(p)].x * (1.0f / 8388608.0f);
    s[PAD(p)] = make_float2(kr * cv, -kr * sv);
  }
  __syncthreads();
  kfs_r2(s, tid);
  kfs_dit<2>(s, tid);
  kfs_dit<8>(s, tid);
  kfs_dit<32>(s, tid);
  kfs_dit<128>(s, tid);
  kfs_dit<512>(s, tid);
#pragma unroll
  for (int m = 0; m < 8; ++m) {
    int q = tid + 256 * m;
    kfc[2048 + (int)(__brev((unsigned)q) >> 21)] = s[PAD(q)];
  }
}

// ---------------------------------------------------------------------------
// Kernel 4: paired real FFT conv, 3-level register FFT; D*y folded into the
// spectrum (conv + D*y = IFFT(U*(K + D)) for t<2048); writes h as bf16 (B,C,T).
// ---------------------------------------------------------------------------
__global__ __launch_bounds__(256) void k_conv(const float* __restrict__ y_tr,
                                              const float2* __restrict__ kf,
                                              const float* __restrict__ D,
                                              ushort_t* __restrict__ h_bf) {
  __shared__ float2 s[4352];
  const int tid = threadIdx.x;
  const int p = blockIdx.x;
  const int b = p >> 7, c = p & 127;
  const float* __restrict__ r1 = y_tr + (size_t)(b * 128 + c) * 2048;
  const float* __restrict__ r2 = y_tr + (size_t)((b + 8) * 128 + c) * 2048;
  ushort_t* __restrict__ hb1 = h_bf + (size_t)(b * 128 + c) * 2048;
  ushort_t* __restrict__ hb2 = h_bf + (size_t)((b + 8) * 128 + c) * 2048;

  const float2 K1 = make_float2(W256R, W256I);
  const float2 K2 = make_float2(W512R, W512I);
  const float2 K3 = make_float2(W768R, W768I);

  float2 v[16];
  float sv, cv;
  // ---- forward phase A: Q=1024 (legs 2,3 zero), Q=256 ----
  {
    float2 ya[8];
#pragma unroll
    for (int e = 0; e < 8; ++e) ya[e] = make_float2(r1[tid + 256 * e], r2[tid + 256 * e]);
    sincospif(-(float)tid * (1.0f / 2048.0f), &sv, &cv);
    const float2 wt = make_float2(cv, sv);
    bf4f_z(ya[0], ya[4], wt,            v[0], v[4], v[8], v[12]);
    bf4f_z(ya[1], ya[5], cmulf(wt, K1), v[1], v[5], v[9], v[13]);
    bf4f_z(ya[2], ya[6], cmulf(wt, K2), v[2], v[6], v[10], v[14]);
    bf4f_z(ya[3], ya[7], cmulf(wt, K3), v[3], v[7], v[11], v[15]);
  }
  sincospif(-(float)tid * (1.0f / 512.0f), &sv, &cv);
  {
    const float2 wq = make_float2(cv, sv);
    bf4f(v[0], v[1], v[2], v[3], wq);
    bf4f(v[4], v[5], v[6], v[7], wq);
    bf4f(v[8], v[9], v[10], v[11], wq);
    bf4f(v[12], v[13], v[14], v[15], wq);
  }
  // ---- exchange 1: write A-pattern, read B-pattern ----
  {
    const int wb0 = tid + (tid >> 4);
#pragma unroll
    for (int e = 0; e < 16; ++e) s[272 * e + wb0] = v[e];
  }
  __syncthreads();
  const int a_ = tid >> 4, b_ = tid & 15;
  const int rbB = 272 * a_ + b_;
#pragma unroll
  for (int e = 0; e < 16; ++e) v[e] = s[rbB + 17 * e];
  // ---- forward phase B: Q=64, Q=16 ----
  sincospif(-(float)b_ * (1.0f / 128.0f), &sv, &cv);
  {
    const float2 wb = make_float2(cv, sv);
    bf4f(v[0], v[4], v[8], v[12], wb);
    bf4f(v[1], v[5], v[9], v[13], cmulf(wb, K1));
    bf4f(v[2], v[6], v[10], v[14], cmulf(wb, K2));
    bf4f(v[3], v[7], v[11], v[15], cmulf(wb, K3));
  }
  sincospif(-(float)b_ * (1.0f / 32.0f), &sv, &cv);
  {
    const float2 w16 = make_float2(cv, sv);
    bf4f(v[0], v[1], v[2], v[3], w16);
    bf4f(v[4], v[5], v[6], v[7], w16);
    bf4f(v[8], v[9], v[10], v[11], w16);
    bf4f(v[12], v[13], v[14], v[15], w16);
  }
  // ---- exchange 2 ----
#pragma unroll
  for (int e = 0; e < 16; ++e) s[rbB + 17 * e] = v[e];
  __syncthreads();
#pragma unroll
  for (int e = 0; e < 16; ++e) v[e] = s[17 * tid + e];
  // ---- forward phase C ----
  bf4f1(v[0], v[4], v[8], v[12]);
  bf4f(v[1], v[5], v[9], v[13], K1);
  bf4f(v[2], v[6], v[10], v[14], K2);
  bf4f(v[3], v[7], v[11], v[15], K3);
  bf4f1(v[0], v[1], v[2], v[3]);
  bf4f1(v[4], v[5], v[6], v[7]);
  bf4f1(v[8], v[9], v[10], v[11]);
  bf4f1(v[12], v[13], v[14], v[15]);
  // ---- spectral multiply with (K + D) (kf pre-scaled by 1/4096) ----
  {
    const float dsc = D[c] * (1.0f / 4096.0f);
    const float2* __restrict__ kfc = kf + (size_t)c * 4096 + 16 * tid;
#pragma unroll
    for (int e = 0; e < 16; ++e) {
      float2 kv = kfc[e];
      kv.x += dsc;
      v[e] = cmulf(v[e], kv);
    }
  }
  // ---- inverse phase C ----
  bf4i1(v[0], v[1], v[2], v[3]);
  bf4i1(v[4], v[5], v[6], v[7]);
  bf4i1(v[8], v[9], v[10], v[11]);
  bf4i1(v[12], v[13], v[14], v[15]);
  bf4i1(v[0], v[4], v[8], v[12]);
  bf4i(v[1], v[5], v[9], v[13], cconj(K1));
  bf4i(v[2], v[6], v[10], v[14], cconj(K2));
  bf4i(v[3], v[7], v[11], v[15], cconj(K3));
  // ---- exchange 3 ----
#pragma unroll
  for (int e = 0; e < 16; ++e) s[17 * tid + e] = v[e];
  __syncthreads();
#pragma unroll
  for (int e = 0; e < 16; ++e) v[e] = s[rbB + 17 * e];
  // ---- inverse phase B ----
  sincospif((float)b_ * (1.0f / 32.0f), &sv, &cv);
  {
    const float2 w16c = make_float2(cv, sv);
    bf4i(v[0], v[1], v[2], v[3], w16c);
    bf4i(v[4], v[5], v[6], v[7], w16c);
    bf4i(v[8], v[9], v[10], v[11], w16c);
    bf4i(v[12], v[13], v[14], v[15], w16c);
  }
  sincospif((float)b_ * (1.0f / 128.0f), &sv, &cv);
  {
    const float2 wbc = make_float2(cv, sv);
    bf4i(v[0], v[4], v[8], v[12], wbc);
    bf4i(v[1], v[5], v[9], v[13], cmulf(wbc, cconj(K1)));
    bf4i(v[2], v[6], v[10], v[14], cmulf(wbc, cconj(K2)));
    bf4i(v[3], v[7], v[11], v[15], cmulf(wbc, cconj(K3)));
  }
  // ---- exchange 4 ----
#pragma unroll
  for (int e = 0; e < 16; ++e) s[rbB + 17 * e] = v[e];
  __syncthreads();
  {
    const int wb0 = tid + (tid >> 4);
#pragma unroll
    for (int e = 0; e < 16; ++e) v[e] = s[272 * e + wb0];
  }
  // ---- inverse phase A: Q=256, then Q=1024 fused with GELU + bf16 store ----
  sincospif((float)tid * (1.0f / 512.0f), &sv, &cv);
  {
    const float2 wqc = make_float2(cv, sv);
    bf4i(v[0], v[1], v[2], v[3], wqc);
    bf4i(v[4], v[5], v[6], v[7], wqc);
    bf4i(v[8], v[9], v[10], v[11], wqc);
    bf4i(v[12], v[13], v[14], v[15], wqc);
  }
  sincospif((float)tid * (1.0f / 2048.0f), &sv, &cv);
  const float2 wtc = make_float2(cv, sv);
  auto fin = [&](float2 va, float2 vb, float2 vc2, float2 vd, float2 u1, int e0) {
    float2 u2 = cmulf(u1, u1);
    float2 tb = cmulf(vb, u2), td = cmulf(vd, u2);
    float2 a1 = cadd(va, tb), b1 = csub(va, tb), c1 = cadd(vc2, td), d1 = csub(vc2, td);
    float2 tc = cmulf(c1, u1), te = cmulf(d1, u1);
    float2 oa = cadd(a1, tc);
    float2 ob = make_float2(b1.x - te.y, b1.y + te.x);
    int i0 = tid + 256 * e0;
    hb1[i0] = f2bf(gelu1(oa.x));
    hb2[i0] = f2bf(gelu1(oa.y));
    hb1[i0 + 1024] = f2bf(gelu1(ob.x));
    hb2[i0 + 1024] = f2bf(gelu1(ob.y));
  };
  fin(v[0], v[4], v[8], v[12], wtc, 0);
  fin(v[1], v[5], v[9], v[13], cmulf(wtc, cconj(K1)), 1);
  fin(v[2], v[6], v[10], v[14], cmulf(wtc, cconj(K2)), 2);
  fin(v[3], v[7], v[11], v[15], cmulf(wtc, cconj(K3)), 3);
}

// ---------------------------------------------------------------------------
// Kernel 5 (MFMA bf16): out[b,t,o] = sum_c h[b,c,t]*W[o,c] + b_out[o] + x[b,t,o]
// grid: 512 = 16 b x 32 t-tiles(64). block 256 = 4 waves; wave w owns t-rows
// [16w,16w+16), 8 o-tiles, K=128 in 4 steps of 32.
// ---------------------------------------------------------------------------
__global__ __launch_bounds__(256) void k_out(const ushort_t* __restrict__ h_bf,
                                             const float* __restrict__ W,
                                             const float* __restrict__ bout,
                                             const float* __restrict__ x,
                                             float* __restrict__ out) {
  __shared__ __align__(16) char smem[52224];
  ushort_t* Wl = (ushort_t*)smem;                  // [128][136]
  ushort_t* hl = (ushort_t*)(smem + 34816);        // [64][136]
  float* ep = (float*)smem;                        // [64][132] (alias, after barrier)
  const int tid = threadIdx.x;
  const int b = blockIdx.x >> 5;
  const int t0 = (blockIdx.x & 31) << 6;

  // stage W (fp32 -> bf16, swizzled: col' = ((cb ^ (o&15))<<3) + (c&7))
  {
    const float4* __restrict__ W4 = (const float4*)W;
#pragma unroll
    for (int r = 0; r < 16; ++r) {
      int idx = tid + 256 * r;  // 128 o x 32 j
      int o = idx >> 5, j = idx & 31;
      float4 w4 = W4[o * 32 + j];
      int sc = (((j >> 1) ^ (o & 15)) << 3) + 4 * (j & 1);
      ushort4 u;
      u.x = f2bf(w4.x); u.y = f2bf(w4.y); u.z = f2bf(w4.z); u.w = f2bf(w4.w);
      *(ushort4*)&Wl[o * 136 + sc] = u;
    }
  }
  // stage h tile (bf16 global (b,c,t) -> LDS [t][c] swizzled)
  {
#pragma unroll
    for (int r = 0; r < 8; ++r) {
      int idx = tid + 256 * r;  // 128 c x 16 t4
      int cc = idx >> 4, t4 = (idx & 15) * 4;
      ushort4 hv = *(const ushort4*)&h_bf[((size_t)(b * 128 + cc)) * 2048 + t0 + t4];
      int cb = cc >> 3, clo = cc & 7;
#pragma unroll
      for (int i = 0; i < 4; ++i) {
        int t = t4 + i;
        hl[t * 136 + (((cb ^ (t & 15)) << 3) + clo)] = ((const ushort_t*)&hv)[i];
      }
    }
  }
  __syncthreads();

  const int l = tid & 63;
  const int w = tid >> 6;
  const int tl = l & 15;
  const int g = l >> 4;
  f32x4 acc[8];
#pragma unroll
  for (int i = 0; i < 8; ++i) acc[i] = (f32x4){0.f, 0.f, 0.f, 0.f};

#pragma unroll
  for (int ks = 0; ks < 4; ++ks) {
    int cb = ks * 4 + g;
    int col = ((cb ^ tl) << 3);
    bf16x8 bfrag = *(const bf16x8*)&hl[(16 * w + tl) * 136 + col];
#pragma unroll
    for (int ot = 0; ot < 8; ++ot) {
      bf16x8 afrag = *(const bf16x8*)&Wl[(ot * 16 + tl) * 136 + col];
      acc[ot] = __builtin_amdgcn_mfma_f32_16x16x32_bf16(afrag, bfrag, acc[ot], 0, 0, 0);
    }
  }
  __syncthreads();
  // epilogue: D[row=o', col=t'] with o' = g*4+r, t' = tl
#pragma unroll
  for (int ot = 0; ot < 8; ++ot) {
#pragma unroll
    for (int r = 0; r < 4; ++r) {
      int o = ot * 16 + g * 4 + r;
      int t = 16 * w + tl;
      ep[t * 132 + o] = acc[ot][r];
    }
  }
  __syncthreads();
#pragma unroll
  for (int r = 0; r < 8; ++r) {
    int idx = tid + 256 * r;  // 64 t x 32 q
    int t = idx >> 5, q = idx & 31;
    float4 v = *(float4*)&ep[t * 132 + 4 * q];
    float4 bo4 = *(const float4*)&bout[4 * q];
    size_t off = ((size_t)b * 2048 + t0 + t) * 128 + 4 * q;
    float4 xv = *(const float4*)&x[off];
    v.x += bo4.x + xv.x;
    v.y += bo4.y + xv.y;
    v.z += bo4.z + xv.z;
    v.w += bo4.w + xv.w;
    *(float4*)&out[off] = v;
  }
}

// ---------------------------------------------------------------------------

extern "C" void kernel_launch(void* const* d_in, const int* in_sizes, int n_in,
                              void* d_out, int out_size, void* d_ws, size_t ws_size,
                              hipStream_t stream) {
  (void)in_sizes; (void)n_in; (void)out_size; (void)ws_size;
  const float* x  = (const float*)d_in[0];
  const float* g  = (const float*)d_in[1];
  const float* be = (const float*)d_in[2];
  const float* Lr = (const float*)d_in[3];
  const float* Li = (const float*)d_in[4];
  const float* Pr = (const float*)d_in[5];
  const float* Pi = (const float*)d_in[6];
  const float* Br = (const float*)d_in[7];
  const float* Bi = (const float*)d_in[8];
  const float* Cr = (const float*)d_in[9];
  const float* Ci = (const float*)d_in[10];
  const float* D  = (const float*)d_in[11];
  const float* W  = (const float*)d_in[12];
  const float* bo = (const float*)d_in[13];
  float* out = (float*)d_out;

  char* ws = (char*)d_ws;
  float*    y_tr = (float*)ws;                    // 16 MiB: y (B,C,T)
  float2*   arr  = (float2*)(ws + (16u << 20));   //  2 MiB: at_roots (C,L)
  float2*   kfb  = (float2*)(ws + (18u << 20));   //  4 MiB: kernel spectrum
  ushort_t* h_bf = (ushort_t*)(ws + (22u << 20)); //  8 MiB: h bf16 (B,C,T)

  hipLaunchKernelGGL(k_ln_t, dim3(1024), dim3(256), 0, stream, x, g, be, y_tr);
  hipLaunchKernelGGL(k_ar,   dim3(512),  dim3(256), 0, stream, Lr, Li, Pr, Pi, Br, Bi, Cr, Ci, arr);
  hipLaunchKernelGGL(k_kf,   dim3(128),  dim3(256), 0, stream, arr, kfb);
  hipLaunchKernelGGL(k_conv, dim3(1024), dim3(256), 0, stream, y_tr, kfb, D, h_bf);
  hipLaunchKernelGGL(k_out,  dim3(512),  dim3(256), 0, stream, h_bf, W, bo, x, out);
}

// Round 6
// 80.406 us; speedup vs baseline: 2.0061x; 1.0708x over previous
//
#include <hip/hip_runtime.h>

// ---------------------------------------------------------------------------
// Problem constants: B=16, T=2048, C=128, N=64, FFT length NF=4096
// ---------------------------------------------------------------------------

#define PAD(i) ((i) + ((i) >> 4))

using bf16x8 = __attribute__((ext_vector_type(8))) short;
using f32x4 = __attribute__((ext_vector_type(4))) float;
typedef unsigned short ushort_t;

static __device__ __forceinline__ float2 cmulf(float2 a, float2 b) {
  return make_float2(a.x * b.x - a.y * b.y, a.x * b.y + a.y * b.x);
}
static __device__ __forceinline__ float2 cadd(float2 a, float2 b) { return make_float2(a.x + b.x, a.y + b.y); }
static __device__ __forceinline__ float2 csub(float2 a, float2 b) { return make_float2(a.x - b.x, a.y - b.y); }
static __device__ __forceinline__ float2 cconj(float2 a) { return make_float2(a.x, -a.y); }
static __device__ __forceinline__ float gelu1(float x) { return 0.5f * x * (1.0f + erff(x * 0.70710678f)); }
static __device__ __forceinline__ ushort_t f2bf(float f) {  // RNE f32->bf16
  unsigned int u = __float_as_uint(f);
  u += 0x7FFFu + ((u >> 16) & 1u);
  return (ushort_t)(u >> 16);
}

template <bool INV>
static __device__ __forceinline__ void bf4g(float2& a, float2& b, float2& c, float2& d, float2 w1) {
  float2 t0 = cadd(a, c), t1 = csub(a, c), t2 = cadd(b, d), t3 = csub(b, d);
  float2 w2 = cmulf(w1, w1), w3 = cmulf(w2, w1);
  float2 o0 = cadd(t0, t2);
  float2 o1 = cmulf(csub(t0, t2), w2);
  float2 o2, o3;
  if (!INV) {
    o2 = cmulf(make_float2(t1.x + t3.y, t1.y - t3.x), w1);
    o3 = cmulf(make_float2(t1.x - t3.y, t1.y + t3.x), w3);
  } else {
    o2 = cmulf(make_float2(t1.x - t3.y, t1.y + t3.x), w1);
    o3 = cmulf(make_float2(t1.x + t3.y, t1.y - t3.x), w3);
  }
  a = o0; b = o1; c = o2; d = o3;
}
static __device__ __forceinline__ void bf4f(float2& a, float2& b, float2& c, float2& d, float2 w1) {
  bf4g<false>(a, b, c, d, w1);
}
static __device__ __forceinline__ void bf4f1(float2& a, float2& b, float2& c, float2& d) {
  float2 t0 = cadd(a, c), t1 = csub(a, c), t2 = cadd(b, d), t3 = csub(b, d);
  a = cadd(t0, t2);
  b = csub(t0, t2);
  c = make_float2(t1.x + t3.y, t1.y - t3.x);
  d = make_float2(t1.x - t3.y, t1.y + t3.x);
}
static __device__ __forceinline__ void bf4f_z(float2 a, float2 b, float2 w1,
                                              float2& o0, float2& o1, float2& o2, float2& o3) {
  float2 w2 = cmulf(w1, w1), w3 = cmulf(w2, w1);
  o0 = cadd(a, b);
  o1 = cmulf(csub(a, b), w2);
  o2 = cmulf(make_float2(a.x + b.y, a.y - b.x), w1);
  o3 = cmulf(make_float2(a.x - b.y, a.y + b.x), w3);
}
template <bool INV>
static __device__ __forceinline__ void bf4h(float2& a, float2& b, float2& c, float2& d, float2 u1) {
  float2 u2 = cmulf(u1, u1);
  float2 tb = cmulf(b, u2), td = cmulf(d, u2);
  float2 a1 = cadd(a, tb), b1 = csub(a, tb), c1 = cadd(c, td), d1 = csub(c, td);
  float2 tc = cmulf(c1, u1), te = cmulf(d1, u1);
  a = cadd(a1, tc);
  c = csub(a1, tc);
  if (INV) {
    b = make_float2(b1.x - te.y, b1.y + te.x);
    d = make_float2(b1.x + te.y, b1.y - te.x);
  } else {
    b = make_float2(b1.x + te.y, b1.y - te.x);
    d = make_float2(b1.x - te.y, b1.y + te.x);
  }
}
static __device__ __forceinline__ void bf4i(float2& a, float2& b, float2& c, float2& d, float2 u1) {
  bf4h<true>(a, b, c, d, u1);
}
static __device__ __forceinline__ void bf4i1(float2& a, float2& b, float2& c, float2& d) {
  float2 a1 = cadd(a, b), b1 = csub(a, b), c1 = cadd(c, d), d1 = csub(c, d);
  a = cadd(a1, c1);
  c = csub(a1, c1);
  b = make_float2(b1.x - d1.y, b1.y + d1.x);
  d = make_float2(b1.x + d1.y, b1.y - d1.x);
}

#define W256R 0.9238795325112867f
#define W256I -0.3826834323650898f
#define W512R 0.7071067811865476f
#define W512I -0.7071067811865476f
#define W768R 0.3826834323650898f
#define W768I -0.9238795325112867f

// ---------------------------------------------------------------------------
// Kernel 1 (fused): blocks [0,1024): LayerNorm+transpose (B,T,C)->(B,C,T).
//                   blocks [1024,1536): at_roots Cauchy sums.
// Independent workloads (memory-bound + VALU-bound) overlap on the CUs.
// ---------------------------------------------------------------------------
__global__ __launch_bounds__(256) void k_ln_ar(
    const float* __restrict__ x, const float* __restrict__ gamma, const float* __restrict__ beta,
    float* __restrict__ y_tr,
    const float* __restrict__ Lr, const float* __restrict__ Li,
    const float* __restrict__ Pr, const float* __restrict__ Pi,
    const float* __restrict__ Br, const float* __restrict__ Bi,
    const float* __restrict__ Cr, const float* __restrict__ Ci,
    float2* __restrict__ arr) {
  __shared__ __align__(16) char sm[17536];
  const int tid = threadIdx.x;
  if (blockIdx.x < 1024) {
    // ---------------- LayerNorm + transpose ----------------
    float* tile = (float*)sm;              // [32*129]
    float* sg = (float*)(sm + 16512);      // [128]
    float* sb = (float*)(sm + 17024);      // [128]
    const int b = blockIdx.x >> 6;
    const int t0 = (blockIdx.x & 63) << 5;
    if (tid < 128) { sg[tid] = gamma[tid]; sb[tid] = beta[tid]; }
    const float4* __restrict__ xb4 = (const float4*)(x + ((size_t)b * 2048 + t0) * 128);
#pragma unroll
    for (int r = 0; r < 4; ++r) {
      int idx = tid + 256 * r;  // 32 t x 32 j
      int t = idx >> 5, j = idx & 31;
      float4 v4 = xb4[idx];
      float* dst = &tile[t * 129 + 4 * j];
      dst[0] = v4.x; dst[1] = v4.y; dst[2] = v4.z; dst[3] = v4.w;
    }
    __syncthreads();
    const int row = tid >> 3, sgp = tid & 7;
    float sum = 0.f, sq = 0.f;
#pragma unroll
    for (int i = 0; i < 16; ++i) {
      float v = tile[row * 129 + sgp * 16 + i];
      sum += v;
      sq += v * v;
    }
    sum += __shfl_xor(sum, 1); sq += __shfl_xor(sq, 1);
    sum += __shfl_xor(sum, 2); sq += __shfl_xor(sq, 2);
    sum += __shfl_xor(sum, 4); sq += __shfl_xor(sq, 4);
    float mean = sum * (1.0f / 128.0f);
    float var = sq * (1.0f / 128.0f) - mean * mean;
    float rstd = 1.0f / sqrtf(var + 1e-5f);
#pragma unroll
    for (int i = 0; i < 16; ++i) {
      int cc = sgp * 16 + i;
      float v = tile[row * 129 + cc];
      tile[row * 129 + cc] = (v - mean) * rstd * sg[cc] + sb[cc];
    }
    __syncthreads();
    float* __restrict__ yb = y_tr + (size_t)b * 128 * 2048 + t0;
#pragma unroll
    for (int r = 0; r < 4; ++r) {
      int idx = tid + 256 * r;  // 128 cc x 8 tl4
      int cc = idx >> 3, tl4 = (idx & 7) * 4;
      float4 o4 = make_float4(tile[(tl4 + 0) * 129 + cc], tile[(tl4 + 1) * 129 + cc],
                              tile[(tl4 + 2) * 129 + cc], tile[(tl4 + 3) * 129 + cc]);
      *(float4*)(yb + (size_t)cc * 2048 + tl4) = o4;
    }
  } else {
    // ---------------- at_roots (DPLR generating function) ----------------
    // NOTE: Omega must use the APPROXIMATE angle (sincosf of theta) exactly
    // like the JAX reference; exact sincospif makes 1+Omega==0 at l=1024 -> NaN.
    float2* sLam = (float2*)sm;
    float2* sv00 = sLam + 64;
    float2* sv01 = sLam + 128;
    float2* sv10 = sLam + 192;
    float2* sv11 = sLam + 256;
    const int id = blockIdx.x - 1024;
    const int c = id >> 2;
    const int slab = id & 3;
    if (tid < 64) {
      int i = c * 64 + tid;
      float lr = fminf(Lr[i], 1e-4f), li = Li[i];
      float pr = Pr[i], pi = Pi[i];
      float br = Br[i], bi = Bi[i];
      float cr = Cr[i], ci = Ci[i];
      sLam[tid] = make_float2(lr, li);
      sv00[tid] = make_float2(cr * br + ci * bi, cr * bi - ci * br);
      sv01[tid] = make_float2(cr * pr + ci * pi, cr * pi - ci * pr);
      sv10[tid] = make_float2(pr * br + pi * bi, pr * bi - pi * br);
      sv11[tid] = make_float2(pr * pr + pi * pi, 0.0f);
    }
    __syncthreads();
#pragma unroll
    for (int kk = 0; kk < 2; ++kk) {
      int l = slab * 512 + tid + 256 * kk;
      float theta = (-6.2831855f * (float)l) * (1.0f / 2048.0f);
      float om_i, om_r;
      sincosf(theta, &om_i, &om_r);
      float pr_ = 1.0f + om_r, pi_ = om_i;
      float mr_ = 1.0f - om_r, mi_ = -om_i;
      float invd = __builtin_amdgcn_rcpf(fmaf(pr_, pr_, pi_ * pi_));
      float gr = 200.0f * ((mr_ * pr_ + mi_ * pi_) * invd);
      float gi = 200.0f * ((mi_ * pr_ - mr_ * pi_) * invd);
      float c2r = 2.0f * pr_ * invd, c2i = -2.0f * pi_ * invd;
      float s00r = 0.f, s00i = 0.f, s01r = 0.f, s01i = 0.f;
      float s10r = 0.f, s10i = 0.f, s11r = 0.f, s11i = 0.f;
#pragma unroll 8
      for (int n = 0; n < 64; ++n) {
        float2 lam = sLam[n];
        float dr = gr - lam.x, di = gi - lam.y;
        float idn = __builtin_amdgcn_rcpf(fmaf(dr, dr, di * di));
        float ir = dr * idn, ii = -di * idn;
        float2 v;
        v = sv00[n]; s00r += v.x * ir - v.y * ii; s00i += v.x * ii + v.y * ir;
        v = sv01[n]; s01r += v.x * ir - v.y * ii; s01i += v.x * ii + v.y * ir;
        v = sv10[n]; s10r += v.x * ir - v.y * ii; s10i += v.x * ii + v.y * ir;
        v = sv11[n]; s11r += v.x * ir - v.y * ii; s11i += v.x * ii + v.y * ir;
      }
      float dr2 = 1.0f + s11r, di2 = s11i;
      float idn2 = __builtin_amdgcn_rcpf(fmaf(dr2, dr2, di2 * di2));
      float rr = dr2 * idn2, ri = -di2 * idn2;
      float t1r = s01r * rr - s01i * ri, t1i = s01r * ri + s01i * rr;
      float t2r = t1r * s10r - t1i * s10i, t2i = t1r * s10i + t1i * s10r;
      float fr = s00r - t2r, fi = s00i - t2i;
      arr[(size_t)c * 2048 + l] = make_float2(c2r * fr - c2i * fi, c2r * fi + c2i * fr);
    }
  }
}

// ---------------------------------------------------------------------------
// Kernel 2: kf via even/odd-bin split (even: reflection identity; odd: 2048 FFTs)
// ---------------------------------------------------------------------------
template <int Q, bool INV>
static __device__ __forceinline__ void kfs_dif(float2* s, int tid) {
  constexpr float SC = (float)(2048 / (4 * Q)) * (1.0f / 1024.0f);
#pragma unroll
  for (int m = 0; m < 2; ++m) {
    int k = tid + 256 * m;
    int j = k & (Q - 1);
    int i = ((k - j) << 2) + j;
    float sv, cv;
    sincospif(INV ? (float)j * SC : -(float)j * SC, &sv, &cv);
    float2 w1 = make_float2(cv, sv);
    float2 a = s[PAD(i)], b = s[PAD(i + Q)], c2 = s[PAD(i + 2 * Q)], d = s[PAD(i + 3 * Q)];
    bf4g<INV>(a, b, c2, d, w1);
    s[PAD(i)] = a; s[PAD(i + Q)] = b; s[PAD(i + 2 * Q)] = c2; s[PAD(i + 3 * Q)] = d;
  }
  __syncthreads();
}
template <int Q>
static __device__ __forceinline__ void kfs_dit(float2* s, int tid) {
  constexpr float SC = (float)(2048 / (4 * Q)) * (1.0f / 1024.0f);
#pragma unroll
  for (int m = 0; m < 2; ++m) {
    int k = tid + 256 * m;
    int j = k & (Q - 1);
    int i = ((k - j) << 2) + j;
    float sv, cv;
    sincospif(-(float)j * SC, &sv, &cv);
    float2 u1 = make_float2(cv, sv);
    float2 a = s[PAD(i)], b = s[PAD(i + Q)], c2 = s[PAD(i + 2 * Q)], d = s[PAD(i + 3 * Q)];
    bf4h<false>(a, b, c2, d, u1);
    s[PAD(i)] = a; s[PAD(i + Q)] = b; s[PAD(i + 2 * Q)] = c2; s[PAD(i + 3 * Q)] = d;
  }
  __syncthreads();
}
static __device__ __forceinline__ void kfs_r2(float2* s, int tid) {
#pragma unroll
  for (int m = 0; m < 4; ++m) {
    int k = tid + 256 * m;
    int i = 2 * k;
    float2 a = s[PAD(i)], b = s[PAD(i + 1)];
    s[PAD(i)] = cadd(a, b);
    s[PAD(i + 1)] = csub(a, b);
  }
  __syncthreads();
}

__global__ __launch_bounds__(256) void k_kf(const float2* __restrict__ arr, float2* __restrict__ kf) {
  __shared__ float2 s[2176];
  const int tid = threadIdx.x;
  const int c = blockIdx.x;
  const float2* __restrict__ ac = arr + (size_t)c * 2048;
  float2* __restrict__ kfc = kf + (size_t)c * 4096;
#pragma unroll
  for (int m = 0; m < 8; ++m) {
    int q = tid + 256 * m;
    float2 aq = ac[q];
    s[PAD(q)] = aq;
    float2 am = ac[(2048 - q) & 2047];
    kfc[__brev((unsigned)q) >> 21] =
        make_float2((aq.x + am.x) * (0.5f / 4096.0f), (aq.y - am.y) * (0.5f / 4096.0f));
  }
  __syncthreads();
  kfs_dif<512, true>(s, tid);
  kfs_dif<128, true>(s, tid);
  kfs_dif<32, true>(s, tid);
  kfs_dif<8, true>(s, tid);
  kfs_dif<2, true>(s, tid);
  kfs_r2(s, tid);
#pragma unroll
  for (int m = 0; m < 8; ++m) {
    int p = tid + 256 * m;
    int t = (int)(__brev((unsigned)p) >> 21);
    float sv, cv;
    sincospif((float)t * (1.0f / 2048.0f), &sv, &cv);
    float kr = s[PAD(p)].x * (1.0f / 8388608.0f);
    s[PAD(p)] = make_float2(kr * cv, -kr * sv);
  }
  __syncthreads();
  kfs_r2(s, tid);
  kfs_dit<2>(s, tid);
  kfs_dit<8>(s, tid);
  kfs_dit<32>(s, tid);
  kfs_dit<128>(s, tid);
  kfs_dit<512>(s, tid);
#pragma unroll
  for (int m = 0; m < 8; ++m) {
    int q = tid + 256 * m;
    kfc[2048 + (int)(__brev((unsigned)q) >> 21)] = s[PAD(q)];
  }
}

// ---------------------------------------------------------------------------
// Kernel 3: paired real FFT conv, 3-level register FFT; D*y folded into the
// spectrum (conv + D*y = IFFT(U*(K + D)) for t<2048); writes h as bf16 (B,C,T).
// ---------------------------------------------------------------------------
__global__ __launch_bounds__(256) void k_conv(const float* __restrict__ y_tr,
                                              const float2* __restrict__ kf,
                                              const float* __restrict__ D,
                                              ushort_t* __restrict__ h_bf) {
  __shared__ float2 s[4352];
  const int tid = threadIdx.x;
  const int p = blockIdx.x;
  const int b = p >> 7, c = p & 127;
  const float* __restrict__ r1 = y_tr + (size_t)(b * 128 + c) * 2048;
  const float* __restrict__ r2 = y_tr + (size_t)((b + 8) * 128 + c) * 2048;
  ushort_t* __restrict__ hb1 = h_bf + (size_t)(b * 128 + c) * 2048;
  ushort_t* __restrict__ hb2 = h_bf + (size_t)((b + 8) * 128 + c) * 2048;

  const float2 K1 = make_float2(W256R, W256I);
  const float2 K2 = make_float2(W512R, W512I);
  const float2 K3 = make_float2(W768R, W768I);

  float2 v[16];
  float sv, cv;
  // ---- forward phase A: Q=1024 (legs 2,3 zero), Q=256 ----
  {
    float2 ya[8];
#pragma unroll
    for (int e = 0; e < 8; ++e) ya[e] = make_float2(r1[tid + 256 * e], r2[tid + 256 * e]);
    sincospif(-(float)tid * (1.0f / 2048.0f), &sv, &cv);
    const float2 wt = make_float2(cv, sv);
    bf4f_z(ya[0], ya[4], wt,            v[0], v[4], v[8], v[12]);
    bf4f_z(ya[1], ya[5], cmulf(wt, K1), v[1], v[5], v[9], v[13]);
    bf4f_z(ya[2], ya[6], cmulf(wt, K2), v[2], v[6], v[10], v[14]);
    bf4f_z(ya[3], ya[7], cmulf(wt, K3), v[3], v[7], v[11], v[15]);
  }
  sincospif(-(float)tid * (1.0f / 512.0f), &sv, &cv);
  {
    const float2 wq = make_float2(cv, sv);
    bf4f(v[0], v[1], v[2], v[3], wq);
    bf4f(v[4], v[5], v[6], v[7], wq);
    bf4f(v[8], v[9], v[10], v[11], wq);
    bf4f(v[12], v[13], v[14], v[15], wq);
  }
  // ---- exchange 1: write A-pattern, read B-pattern ----
  {
    const int wb0 = tid + (tid >> 4);
#pragma unroll
    for (int e = 0; e < 16; ++e) s[272 * e + wb0] = v[e];
  }
  __syncthreads();
  const int a_ = tid >> 4, b_ = tid & 15;
  const int rbB = 272 * a_ + b_;
#pragma unroll
  for (int e = 0; e < 16; ++e) v[e] = s[rbB + 17 * e];
  // ---- forward phase B: Q=64, Q=16 ----
  sincospif(-(float)b_ * (1.0f / 128.0f), &sv, &cv);
  {
    const float2 wb = make_float2(cv, sv);
    bf4f(v[0], v[4], v[8], v[12], wb);
    bf4f(v[1], v[5], v[9], v[13], cmulf(wb, K1));
    bf4f(v[2], v[6], v[10], v[14], cmulf(wb, K2));
    bf4f(v[3], v[7], v[11], v[15], cmulf(wb, K3));
  }
  sincospif(-(float)b_ * (1.0f / 32.0f), &sv, &cv);
  {
    const float2 w16 = make_float2(cv, sv);
    bf4f(v[0], v[1], v[2], v[3], w16);
    bf4f(v[4], v[5], v[6], v[7], w16);
    bf4f(v[8], v[9], v[10], v[11], w16);
    bf4f(v[12], v[13], v[14], v[15], w16);
  }
  // ---- exchange 2 ----
#pragma unroll
  for (int e = 0; e < 16; ++e) s[rbB + 17 * e] = v[e];
  __syncthreads();
#pragma unroll
  for (int e = 0; e < 16; ++e) v[e] = s[17 * tid + e];
  // ---- forward phase C ----
  bf4f1(v[0], v[4], v[8], v[12]);
  bf4f(v[1], v[5], v[9], v[13], K1);
  bf4f(v[2], v[6], v[10], v[14], K2);
  bf4f(v[3], v[7], v[11], v[15], K3);
  bf4f1(v[0], v[1], v[2], v[3]);
  bf4f1(v[4], v[5], v[6], v[7]);
  bf4f1(v[8], v[9], v[10], v[11]);
  bf4f1(v[12], v[13], v[14], v[15]);
  // ---- spectral multiply with (K + D) (kf pre-scaled by 1/4096) ----
  {
    const float dsc = D[c] * (1.0f / 4096.0f);
    const float2* __restrict__ kfc = kf + (size_t)c * 4096 + 16 * tid;
#pragma unroll
    for (int e = 0; e < 16; ++e) {
      float2 kv = kfc[e];
      kv.x += dsc;
      v[e] = cmulf(v[e], kv);
    }
  }
  // ---- inverse phase C ----
  bf4i1(v[0], v[1], v[2], v[3]);
  bf4i1(v[4], v[5], v[6], v[7]);
  bf4i1(v[8], v[9], v[10], v[11]);
  bf4i1(v[12], v[13], v[14], v[15]);
  bf4i1(v[0], v[4], v[8], v[12]);
  bf4i(v[1], v[5], v[9], v[13], cconj(K1));
  bf4i(v[2], v[6], v[10], v[14], cconj(K2));
  bf4i(v[3], v[7], v[11], v[15], cconj(K3));
  // ---- exchange 3 ----
#pragma unroll
  for (int e = 0; e < 16; ++e) s[17 * tid + e] = v[e];
  __syncthreads();
#pragma unroll
  for (int e = 0; e < 16; ++e) v[e] = s[rbB + 17 * e];
  // ---- inverse phase B ----
  sincospif((float)b_ * (1.0f / 32.0f), &sv, &cv);
  {
    const float2 w16c = make_float2(cv, sv);
    bf4i(v[0], v[1], v[2], v[3], w16c);
    bf4i(v[4], v[5], v[6], v[7], w16c);
    bf4i(v[8], v[9], v[10], v[11], w16c);
    bf4i(v[12], v[13], v[14], v[15], w16c);
  }
  sincospif((float)b_ * (1.0f / 128.0f), &sv, &cv);
  {
    const float2 wbc = make_float2(cv, sv);
    bf4i(v[0], v[4], v[8], v[12], wbc);
    bf4i(v[1], v[5], v[9], v[13], cmulf(wbc, cconj(K1)));
    bf4i(v[2], v[6], v[10], v[14], cmulf(wbc, cconj(K2)));
    bf4i(v[3], v[7], v[11], v[15], cmulf(wbc, cconj(K3)));
  }
  // ---- exchange 4 ----
#pragma unroll
  for (int e = 0; e < 16; ++e) s[rbB + 17 * e] = v[e];
  __syncthreads();
  {
    const int wb0 = tid + (tid >> 4);
#pragma unroll
    for (int e = 0; e < 16; ++e) v[e] = s[272 * e + wb0];
  }
  // ---- inverse phase A: Q=256, then Q=1024 fused with GELU + bf16 store ----
  sincospif((float)tid * (1.0f / 512.0f), &sv, &cv);
  {
    const float2 wqc = make_float2(cv, sv);
    bf4i(v[0], v[1], v[2], v[3], wqc);
    bf4i(v[4], v[5], v[6], v[7], wqc);
    bf4i(v[8], v[9], v[10], v[11], wqc);
    bf4i(v[12], v[13], v[14], v[15], wqc);
  }
  sincospif((float)tid * (1.0f / 2048.0f), &sv, &cv);
  const float2 wtc = make_float2(cv, sv);
  auto fin = [&](float2 va, float2 vb, float2 vc2, float2 vd, float2 u1, int e0) {
    float2 u2 = cmulf(u1, u1);
    float2 tb = cmulf(vb, u2), td = cmulf(vd, u2);
    float2 a1 = cadd(va, tb), b1 = csub(va, tb), c1 = cadd(vc2, td), d1 = csub(vc2, td);
    float2 tc = cmulf(c1, u1), te = cmulf(d1, u1);
    float2 oa = cadd(a1, tc);
    float2 ob = make_float2(b1.x - te.y, b1.y + te.x);
    int i0 = tid + 256 * e0;
    hb1[i0] = f2bf(gelu1(oa.x));
    hb2[i0] = f2bf(gelu1(oa.y));
    hb1[i0 + 1024] = f2bf(gelu1(ob.x));
    hb2[i0 + 1024] = f2bf(gelu1(ob.y));
  };
  fin(v[0], v[4], v[8], v[12], wtc, 0);
  fin(v[1], v[5], v[9], v[13], cmulf(wtc, cconj(K1)), 1);
  fin(v[2], v[6], v[10], v[14], cmulf(wtc, cconj(K2)), 2);
  fin(v[3], v[7], v[11], v[15], cmulf(wtc, cconj(K3)), 3);
}

// ---------------------------------------------------------------------------
// Kernel 4 (MFMA bf16): out[b,t,o] = sum_c h[b,c,t]*W[o,c] + b_out[o] + x[b,t,o]
// Direct epilogue stores from the accumulator layout (no LDS round-trip).
// ---------------------------------------------------------------------------
__global__ __launch_bounds__(256) void k_out(const ushort_t* __restrict__ h_bf,
                                             const float* __restrict__ W,
                                             const float* __restrict__ bout,
                                             const float* __restrict__ x,
                                             float* __restrict__ out) {
  __shared__ __align__(16) char smem[52224];
  ushort_t* Wl = (ushort_t*)smem;                  // [128][136]
  ushort_t* hl = (ushort_t*)(smem + 34816);        // [64][136]
  const int tid = threadIdx.x;
  const int b = blockIdx.x >> 5;
  const int t0 = (blockIdx.x & 31) << 6;

  // stage W (fp32 -> bf16, swizzled: col' = ((cb ^ (o&15))<<3) + (c&7))
  {
    const float4* __restrict__ W4 = (const float4*)W;
#pragma unroll
    for (int r = 0; r < 16; ++r) {
      int idx = tid + 256 * r;  // 128 o x 32 j
      int o = idx >> 5, j = idx & 31;
      float4 w4 = W4[o * 32 + j];
      int sc = (((j >> 1) ^ (o & 15)) << 3) + 4 * (j & 1);
      ushort4 u;
      u.x = f2bf(w4.x); u.y = f2bf(w4.y); u.z = f2bf(w4.z); u.w = f2bf(w4.w);
      *(ushort4*)&Wl[o * 136 + sc] = u;
    }
  }
  // stage h tile (bf16 global (b,c,t) -> LDS [t][c] swizzled)
  {
#pragma unroll
    for (int r = 0; r < 8; ++r) {
      int idx = tid + 256 * r;  // 128 c x 16 t4
      int cc = idx >> 4, t4 = (idx & 15) * 4;
      ushort4 hv = *(const ushort4*)&h_bf[((size_t)(b * 128 + cc)) * 2048 + t0 + t4];
      int cb = cc >> 3, clo = cc & 7;
#pragma unroll
      for (int i = 0; i < 4; ++i) {
        int t = t4 + i;
        hl[t * 136 + (((cb ^ (t & 15)) << 3) + clo)] = ((const ushort_t*)&hv)[i];
      }
    }
  }
  __syncthreads();

  const int l = tid & 63;
  const int w = tid >> 6;
  const int tl = l & 15;
  const int g = l >> 4;
  f32x4 acc[8];
#pragma unroll
  for (int i = 0; i < 8; ++i) acc[i] = (f32x4){0.f, 0.f, 0.f, 0.f};

#pragma unroll
  for (int ks = 0; ks < 4; ++ks) {
    int cb = ks * 4 + g;
    int col = ((cb ^ tl) << 3);
    bf16x8 bfrag = *(const bf16x8*)&hl[(16 * w + tl) * 136 + col];
#pragma unroll
    for (int ot = 0; ot < 8; ++ot) {
      bf16x8 afrag = *(const bf16x8*)&Wl[(ot * 16 + tl) * 136 + col];
      acc[ot] = __builtin_amdgcn_mfma_f32_16x16x32_bf16(afrag, bfrag, acc[ot], 0, 0, 0);
    }
  }
  // direct epilogue: acc[ot][r] = out[o=16ot+4g+r][t=16w+tl]
  const int t = t0 + 16 * w + tl;
  const size_t rowoff = ((size_t)b * 2048 + t) * 128;
#pragma unroll
  for (int ot = 0; ot < 8; ++ot) {
    int o = ot * 16 + g * 4;
    float4 xv = *(const float4*)&x[rowoff + o];
    float4 bo4 = *(const float4*)&bout[o];
    float4 v;
    v.x = acc[ot][0] + bo4.x + xv.x;
    v.y = acc[ot][1] + bo4.y + xv.y;
    v.z = acc[ot][2] + bo4.z + xv.z;
    v.w = acc[ot][3] + bo4.w + xv.w;
    *(float4*)&out[rowoff + o] = v;
  }
}

// ---------------------------------------------------------------------------

extern "C" void kernel_launch(void* const* d_in, const int* in_sizes, int n_in,
                              void* d_out, int out_size, void* d_ws, size_t ws_size,
                              hipStream_t stream) {
  (void)in_sizes; (void)n_in; (void)out_size; (void)ws_size;
  const float* x  = (const float*)d_in[0];
  const float* g  = (const float*)d_in[1];
  const float* be = (const float*)d_in[2];
  const float* Lr = (const float*)d_in[3];
  const float* Li = (const float*)d_in[4];
  const float* Pr = (const float*)d_in[5];
  const float* Pi = (const float*)d_in[6];
  const float* Br = (const float*)d_in[7];
  const float* Bi = (const float*)d_in[8];
  const float* Cr = (const float*)d_in[9];
  const float* Ci = (const float*)d_in[10];
  const float* D  = (const float*)d_in[11];
  const float* W  = (const float*)d_in[12];
  const float* bo = (const float*)d_in[13];
  float* out = (float*)d_out;

  char* ws = (char*)d_ws;
  float*    y_tr = (float*)ws;                    // 16 MiB: y (B,C,T)
  float2*   arr  = (float2*)(ws + (16u << 20));   //  2 MiB: at_roots (C,L)
  float2*   kfb  = (float2*)(ws + (18u << 20));   //  4 MiB: kernel spectrum
  ushort_t* h_bf = (ushort_t*)(ws + (22u << 20)); //  8 MiB: h bf16 (B,C,T)

  hipLaunchKernelGGL(k_ln_ar, dim3(1536), dim3(256), 0, stream,
                     x, g, be, y_tr, Lr, Li, Pr, Pi, Br, Bi, Cr, Ci, arr);
  hipLaunchKernelGGL(k_kf,   dim3(128),  dim3(256), 0, stream, arr, kfb);
  hipLaunchKernelGGL(k_conv, dim3(1024), dim3(256), 0, stream, y_tr, kfb, D, h_bf);
  hipLaunchKernelGGL(k_out,  dim3(512),  dim3(256), 0, stream, h_bf, W, bo, x, out);
}

// Round 7
// 77.004 us; speedup vs baseline: 2.0948x; 1.0442x over previous
//
#include <hip/hip_runtime.h>

// ---------------------------------------------------------------------------
// Problem constants: B=16, T=2048, C=128, N=64, FFT length NF=4096
// ---------------------------------------------------------------------------

#define PAD(i) ((i) + ((i) >> 4))

using bf16x8 = __attribute__((ext_vector_type(8))) short;
using f32x4 = __attribute__((ext_vector_type(4))) float;
typedef unsigned short ushort_t;

static __device__ __forceinline__ float2 cmulf(float2 a, float2 b) {
  return make_float2(a.x * b.x - a.y * b.y, a.x * b.y + a.y * b.x);
}
static __device__ __forceinline__ float2 cadd(float2 a, float2 b) { return make_float2(a.x + b.x, a.y + b.y); }
static __device__ __forceinline__ float2 csub(float2 a, float2 b) { return make_float2(a.x - b.x, a.y - b.y); }
static __device__ __forceinline__ float2 cconj(float2 a) { return make_float2(a.x, -a.y); }
static __device__ __forceinline__ float gelu1(float x) { return 0.5f * x * (1.0f + erff(x * 0.70710678f)); }
static __device__ __forceinline__ ushort_t f2bf(float f) {  // RNE f32->bf16
  unsigned int u = __float_as_uint(f);
  u += 0x7FFFu + ((u >> 16) & 1u);
  return (ushort_t)(u >> 16);
}
static __device__ __forceinline__ float bf2f(ushort_t u) {
  return __uint_as_float(((unsigned int)u) << 16);
}

template <bool INV>
static __device__ __forceinline__ void bf4g(float2& a, float2& b, float2& c, float2& d, float2 w1) {
  float2 t0 = cadd(a, c), t1 = csub(a, c), t2 = cadd(b, d), t3 = csub(b, d);
  float2 w2 = cmulf(w1, w1), w3 = cmulf(w2, w1);
  float2 o0 = cadd(t0, t2);
  float2 o1 = cmulf(csub(t0, t2), w2);
  float2 o2, o3;
  if (!INV) {
    o2 = cmulf(make_float2(t1.x + t3.y, t1.y - t3.x), w1);
    o3 = cmulf(make_float2(t1.x - t3.y, t1.y + t3.x), w3);
  } else {
    o2 = cmulf(make_float2(t1.x - t3.y, t1.y + t3.x), w1);
    o3 = cmulf(make_float2(t1.x + t3.y, t1.y - t3.x), w3);
  }
  a = o0; b = o1; c = o2; d = o3;
}
static __device__ __forceinline__ void bf4f(float2& a, float2& b, float2& c, float2& d, float2 w1) {
  bf4g<false>(a, b, c, d, w1);
}
static __device__ __forceinline__ void bf4f1(float2& a, float2& b, float2& c, float2& d) {
  float2 t0 = cadd(a, c), t1 = csub(a, c), t2 = cadd(b, d), t3 = csub(b, d);
  a = cadd(t0, t2);
  b = csub(t0, t2);
  c = make_float2(t1.x + t3.y, t1.y - t3.x);
  d = make_float2(t1.x - t3.y, t1.y + t3.x);
}
static __device__ __forceinline__ void bf4f_z(float2 a, float2 b, float2 w1,
                                              float2& o0, float2& o1, float2& o2, float2& o3) {
  float2 w2 = cmulf(w1, w1), w3 = cmulf(w2, w1);
  o0 = cadd(a, b);
  o1 = cmulf(csub(a, b), w2);
  o2 = cmulf(make_float2(a.x + b.y, a.y - b.x), w1);
  o3 = cmulf(make_float2(a.x - b.y, a.y + b.x), w3);
}
template <bool INV>
static __device__ __forceinline__ void bf4h(float2& a, float2& b, float2& c, float2& d, float2 u1) {
  float2 u2 = cmulf(u1, u1);
  float2 tb = cmulf(b, u2), td = cmulf(d, u2);
  float2 a1 = cadd(a, tb), b1 = csub(a, tb), c1 = cadd(c, td), d1 = csub(c, td);
  float2 tc = cmulf(c1, u1), te = cmulf(d1, u1);
  a = cadd(a1, tc);
  c = csub(a1, tc);
  if (INV) {
    b = make_float2(b1.x - te.y, b1.y + te.x);
    d = make_float2(b1.x + te.y, b1.y - te.x);
  } else {
    b = make_float2(b1.x + te.y, b1.y - te.x);
    d = make_float2(b1.x - te.y, b1.y + te.x);
  }
}
static __device__ __forceinline__ void bf4i(float2& a, float2& b, float2& c, float2& d, float2 u1) {
  bf4h<true>(a, b, c, d, u1);
}
static __device__ __forceinline__ void bf4i1(float2& a, float2& b, float2& c, float2& d) {
  float2 a1 = cadd(a, b), b1 = csub(a, b), c1 = cadd(c, d), d1 = csub(c, d);
  a = cadd(a1, c1);
  c = csub(a1, c1);
  b = make_float2(b1.x - d1.y, b1.y + d1.x);
  d = make_float2(b1.x + d1.y, b1.y - d1.x);
}

#define W256R 0.9238795325112867f
#define W256I -0.3826834323650898f
#define W512R 0.7071067811865476f
#define W512I -0.7071067811865476f
#define W768R 0.3826834323650898f
#define W768I -0.9238795325112867f

// ---------------------------------------------------------------------------
// Kernel 1 (fused): blocks [0,1024): LayerNorm+transpose (B,T,C)->(B,C,T) bf16.
//                   blocks [1024,1536): at_roots Cauchy sums.
// ---------------------------------------------------------------------------
__global__ __launch_bounds__(256) void k_ln_ar(
    const float* __restrict__ x, const float* __restrict__ gamma, const float* __restrict__ beta,
    ushort_t* __restrict__ y_bf,
    const float* __restrict__ Lr, const float* __restrict__ Li,
    const float* __restrict__ Pr, const float* __restrict__ Pi,
    const float* __restrict__ Br, const float* __restrict__ Bi,
    const float* __restrict__ Cr, const float* __restrict__ Ci,
    float2* __restrict__ arr) {
  __shared__ __align__(16) char sm[17536];
  const int tid = threadIdx.x;
  if (blockIdx.x < 1024) {
    // ---------------- LayerNorm + transpose ----------------
    float* tile = (float*)sm;              // [32*129]
    float* sg = (float*)(sm + 16512);      // [128]
    float* sb = (float*)(sm + 17024);      // [128]
    const int b = blockIdx.x >> 6;
    const int t0 = (blockIdx.x & 63) << 5;
    if (tid < 128) { sg[tid] = gamma[tid]; sb[tid] = beta[tid]; }
    const float4* __restrict__ xb4 = (const float4*)(x + ((size_t)b * 2048 + t0) * 128);
#pragma unroll
    for (int r = 0; r < 4; ++r) {
      int idx = tid + 256 * r;  // 32 t x 32 j
      int t = idx >> 5, j = idx & 31;
      float4 v4 = xb4[idx];
      float* dst = &tile[t * 129 + 4 * j];
      dst[0] = v4.x; dst[1] = v4.y; dst[2] = v4.z; dst[3] = v4.w;
    }
    __syncthreads();
    const int row = tid >> 3, sgp = tid & 7;
    float sum = 0.f, sq = 0.f;
#pragma unroll
    for (int i = 0; i < 16; ++i) {
      float v = tile[row * 129 + sgp * 16 + i];
      sum += v;
      sq += v * v;
    }
    sum += __shfl_xor(sum, 1); sq += __shfl_xor(sq, 1);
    sum += __shfl_xor(sum, 2); sq += __shfl_xor(sq, 2);
    sum += __shfl_xor(sum, 4); sq += __shfl_xor(sq, 4);
    float mean = sum * (1.0f / 128.0f);
    float var = sq * (1.0f / 128.0f) - mean * mean;
    float rstd = 1.0f / sqrtf(var + 1e-5f);
#pragma unroll
    for (int i = 0; i < 16; ++i) {
      int cc = sgp * 16 + i;
      float v = tile[row * 129 + cc];
      tile[row * 129 + cc] = (v - mean) * rstd * sg[cc] + sb[cc];
    }
    __syncthreads();
    ushort_t* __restrict__ yb = y_bf + (size_t)b * 128 * 2048 + t0;
#pragma unroll
    for (int r = 0; r < 4; ++r) {
      int idx = tid + 256 * r;  // 128 cc x 8 tl4
      int cc = idx >> 3, tl4 = (idx & 7) * 4;
      ushort4 o4;
      o4.x = f2bf(tile[(tl4 + 0) * 129 + cc]);
      o4.y = f2bf(tile[(tl4 + 1) * 129 + cc]);
      o4.z = f2bf(tile[(tl4 + 2) * 129 + cc]);
      o4.w = f2bf(tile[(tl4 + 3) * 129 + cc]);
      *(ushort4*)(yb + (size_t)cc * 2048 + tl4) = o4;
    }
  } else {
    // ---------------- at_roots (DPLR generating function) ----------------
    // NOTE: Omega must use the APPROXIMATE angle (sincosf of theta) exactly
    // like the JAX reference; exact sincospif makes 1+Omega==0 at l=1024 -> NaN.
    float2* sLam = (float2*)sm;
    float2* sv00 = sLam + 64;
    float2* sv01 = sLam + 128;
    float2* sv10 = sLam + 192;
    float2* sv11 = sLam + 256;
    const int id = blockIdx.x - 1024;
    const int c = id >> 2;
    const int slab = id & 3;
    if (tid < 64) {
      int i = c * 64 + tid;
      float lr = fminf(Lr[i], 1e-4f), li = Li[i];
      float pr = Pr[i], pi = Pi[i];
      float br = Br[i], bi = Bi[i];
      float cr = Cr[i], ci = Ci[i];
      sLam[tid] = make_float2(lr, li);
      sv00[tid] = make_float2(cr * br + ci * bi, cr * bi - ci * br);
      sv01[tid] = make_float2(cr * pr + ci * pi, cr * pi - ci * pr);
      sv10[tid] = make_float2(pr * br + pi * bi, pr * bi - pi * br);
      sv11[tid] = make_float2(pr * pr + pi * pi, 0.0f);
    }
    __syncthreads();
#pragma unroll
    for (int kk = 0; kk < 2; ++kk) {
      int l = slab * 512 + tid + 256 * kk;
      float theta = (-6.2831855f * (float)l) * (1.0f / 2048.0f);
      float om_i, om_r;
      sincosf(theta, &om_i, &om_r);
      float pr_ = 1.0f + om_r, pi_ = om_i;
      float mr_ = 1.0f - om_r, mi_ = -om_i;
      float invd = __builtin_amdgcn_rcpf(fmaf(pr_, pr_, pi_ * pi_));
      float gr = 200.0f * ((mr_ * pr_ + mi_ * pi_) * invd);
      float gi = 200.0f * ((mi_ * pr_ - mr_ * pi_) * invd);
      float c2r = 2.0f * pr_ * invd, c2i = -2.0f * pi_ * invd;
      float s00r = 0.f, s00i = 0.f, s01r = 0.f, s01i = 0.f;
      float s10r = 0.f, s10i = 0.f, s11r = 0.f, s11i = 0.f;
#pragma unroll 8
      for (int n = 0; n < 64; ++n) {
        float2 lam = sLam[n];
        float dr = gr - lam.x, di = gi - lam.y;
        float idn = __builtin_amdgcn_rcpf(fmaf(dr, dr, di * di));
        float ir = dr * idn, ii = -di * idn;
        float2 v;
        v = sv00[n]; s00r += v.x * ir - v.y * ii; s00i += v.x * ii + v.y * ir;
        v = sv01[n]; s01r += v.x * ir - v.y * ii; s01i += v.x * ii + v.y * ir;
        v = sv10[n]; s10r += v.x * ir - v.y * ii; s10i += v.x * ii + v.y * ir;
        v = sv11[n]; s11r += v.x * ir - v.y * ii; s11i += v.x * ii + v.y * ir;
      }
      float dr2 = 1.0f + s11r, di2 = s11i;
      float idn2 = __builtin_amdgcn_rcpf(fmaf(dr2, dr2, di2 * di2));
      float rr = dr2 * idn2, ri = -di2 * idn2;
      float t1r = s01r * rr - s01i * ri, t1i = s01r * ri + s01i * rr;
      float t2r = t1r * s10r - t1i * s10i, t2i = t1r * s10i + t1i * s10r;
      float fr = s00r - t2r, fi = s00i - t2i;
      arr[(size_t)c * 2048 + l] = make_float2(c2r * fr - c2i * fi, c2r * fi + c2i * fr);
    }
  }
}

// ---------------------------------------------------------------------------
// Kernel 2: kf via even/odd-bin split. 512 threads/block (1 radix-4 butterfly
// per thread per stage) to halve serial stage depth.
// ---------------------------------------------------------------------------
template <int Q, bool INV>
static __device__ __forceinline__ void kfs_dif(float2* s, int tid) {
  constexpr float SC = (float)(2048 / (4 * Q)) * (1.0f / 1024.0f);
  int k = tid;  // [0,512)
  int j = k & (Q - 1);
  int i = ((k - j) << 2) + j;
  float sv, cv;
  sincospif(INV ? (float)j * SC : -(float)j * SC, &sv, &cv);
  float2 w1 = make_float2(cv, sv);
  float2 a = s[PAD(i)], b = s[PAD(i + Q)], c2 = s[PAD(i + 2 * Q)], d = s[PAD(i + 3 * Q)];
  bf4g<INV>(a, b, c2, d, w1);
  s[PAD(i)] = a; s[PAD(i + Q)] = b; s[PAD(i + 2 * Q)] = c2; s[PAD(i + 3 * Q)] = d;
  __syncthreads();
}
template <int Q>
static __device__ __forceinline__ void kfs_dit(float2* s, int tid) {
  constexpr float SC = (float)(2048 / (4 * Q)) * (1.0f / 1024.0f);
  int k = tid;
  int j = k & (Q - 1);
  int i = ((k - j) << 2) + j;
  float sv, cv;
  sincospif(-(float)j * SC, &sv, &cv);
  float2 u1 = make_float2(cv, sv);
  float2 a = s[PAD(i)], b = s[PAD(i + Q)], c2 = s[PAD(i + 2 * Q)], d = s[PAD(i + 3 * Q)];
  bf4h<false>(a, b, c2, d, u1);
  s[PAD(i)] = a; s[PAD(i + Q)] = b; s[PAD(i + 2 * Q)] = c2; s[PAD(i + 3 * Q)] = d;
  __syncthreads();
}
static __device__ __forceinline__ void kfs_r2(float2* s, int tid) {
#pragma unroll
  for (int m = 0; m < 2; ++m) {
    int k = tid + 512 * m;  // [0,1024)
    int i = 2 * k;
    float2 a = s[PAD(i)], b = s[PAD(i + 1)];
    s[PAD(i)] = cadd(a, b);
    s[PAD(i + 1)] = csub(a, b);
  }
  __syncthreads();
}

__global__ __launch_bounds__(512) void k_kf(const float2* __restrict__ arr, float2* __restrict__ kf) {
  __shared__ float2 s[2176];
  const int tid = threadIdx.x;
  const int c = blockIdx.x;
  const float2* __restrict__ ac = arr + (size_t)c * 2048;
  float2* __restrict__ kfc = kf + (size_t)c * 4096;
#pragma unroll
  for (int m = 0; m < 4; ++m) {
    int q = tid + 512 * m;
    float2 aq = ac[q];
    s[PAD(q)] = aq;
    float2 am = ac[(2048 - q) & 2047];
    kfc[__brev((unsigned)q) >> 21] =
        make_float2((aq.x + am.x) * (0.5f / 4096.0f), (aq.y - am.y) * (0.5f / 4096.0f));
  }
  __syncthreads();
  kfs_dif<512, true>(s, tid);
  kfs_dif<128, true>(s, tid);
  kfs_dif<32, true>(s, tid);
  kfs_dif<8, true>(s, tid);
  kfs_dif<2, true>(s, tid);
  kfs_r2(s, tid);
#pragma unroll
  for (int m = 0; m < 4; ++m) {
    int p = tid + 512 * m;
    int t = (int)(__brev((unsigned)p) >> 21);
    float sv, cv;
    sincospif((float)t * (1.0f / 2048.0f), &sv, &cv);
    float kr = s[PAD(p)].x * (1.0f / 8388608.0f);
    s[PAD(p)] = make_float2(kr * cv, -kr * sv);
  }
  __syncthreads();
  kfs_r2(s, tid);
  kfs_dit<2>(s, tid);
  kfs_dit<8>(s, tid);
  kfs_dit<32>(s, tid);
  kfs_dit<128>(s, tid);
  kfs_dit<512>(s, tid);
#pragma unroll
  for (int m = 0; m < 4; ++m) {
    int q = tid + 512 * m;
    kfc[2048 + (int)(__brev((unsigned)q) >> 21)] = s[PAD(q)];
  }
}

// ---------------------------------------------------------------------------
// Kernel 3: paired real FFT conv (y read as bf16), 3-level register FFT;
// D*y folded into spectrum; writes h as bf16 (B,C,T).
// ---------------------------------------------------------------------------
__global__ __launch_bounds__(256) void k_conv(const ushort_t* __restrict__ y_bf,
                                              const float2* __restrict__ kf,
                                              const float* __restrict__ D,
                                              ushort_t* __restrict__ h_bf) {
  __shared__ float2 s[4352];
  const int tid = threadIdx.x;
  const int p = blockIdx.x;
  const int b = p >> 7, c = p & 127;
  const ushort_t* __restrict__ r1 = y_bf + (size_t)(b * 128 + c) * 2048;
  const ushort_t* __restrict__ r2 = y_bf + (size_t)((b + 8) * 128 + c) * 2048;
  ushort_t* __restrict__ hb1 = h_bf + (size_t)(b * 128 + c) * 2048;
  ushort_t* __restrict__ hb2 = h_bf + (size_t)((b + 8) * 128 + c) * 2048;

  const float2 K1 = make_float2(W256R, W256I);
  const float2 K2 = make_float2(W512R, W512I);
  const float2 K3 = make_float2(W768R, W768I);

  float2 v[16];
  float sv, cv;
  // ---- forward phase A: Q=1024 (legs 2,3 zero), Q=256 ----
  {
    float2 ya[8];
#pragma unroll
    for (int e = 0; e < 8; ++e)
      ya[e] = make_float2(bf2f(r1[tid + 256 * e]), bf2f(r2[tid + 256 * e]));
    sincospif(-(float)tid * (1.0f / 2048.0f), &sv, &cv);
    const float2 wt = make_float2(cv, sv);
    bf4f_z(ya[0], ya[4], wt,            v[0], v[4], v[8], v[12]);
    bf4f_z(ya[1], ya[5], cmulf(wt, K1), v[1], v[5], v[9], v[13]);
    bf4f_z(ya[2], ya[6], cmulf(wt, K2), v[2], v[6], v[10], v[14]);
    bf4f_z(ya[3], ya[7], cmulf(wt, K3), v[3], v[7], v[11], v[15]);
  }
  sincospif(-(float)tid * (1.0f / 512.0f), &sv, &cv);
  {
    const float2 wq = make_float2(cv, sv);
    bf4f(v[0], v[1], v[2], v[3], wq);
    bf4f(v[4], v[5], v[6], v[7], wq);
    bf4f(v[8], v[9], v[10], v[11], wq);
    bf4f(v[12], v[13], v[14], v[15], wq);
  }
  // ---- exchange 1: write A-pattern, read B-pattern ----
  {
    const int wb0 = tid + (tid >> 4);
#pragma unroll
    for (int e = 0; e < 16; ++e) s[272 * e + wb0] = v[e];
  }
  __syncthreads();
  const int a_ = tid >> 4, b_ = tid & 15;
  const int rbB = 272 * a_ + b_;
#pragma unroll
  for (int e = 0; e < 16; ++e) v[e] = s[rbB + 17 * e];
  // ---- forward phase B: Q=64, Q=16 ----
  sincospif(-(float)b_ * (1.0f / 128.0f), &sv, &cv);
  {
    const float2 wb = make_float2(cv, sv);
    bf4f(v[0], v[4], v[8], v[12], wb);
    bf4f(v[1], v[5], v[9], v[13], cmulf(wb, K1));
    bf4f(v[2], v[6], v[10], v[14], cmulf(wb, K2));
    bf4f(v[3], v[7], v[11], v[15], cmulf(wb, K3));
  }
  sincospif(-(float)b_ * (1.0f / 32.0f), &sv, &cv);
  {
    const float2 w16 = make_float2(cv, sv);
    bf4f(v[0], v[1], v[2], v[3], w16);
    bf4f(v[4], v[5], v[6], v[7], w16);
    bf4f(v[8], v[9], v[10], v[11], w16);
    bf4f(v[12], v[13], v[14], v[15], w16);
  }
  // ---- exchange 2 ----
#pragma unroll
  for (int e = 0; e < 16; ++e) s[rbB + 17 * e] = v[e];
  __syncthreads();
#pragma unroll
  for (int e = 0; e < 16; ++e) v[e] = s[17 * tid + e];
  // ---- forward phase C ----
  bf4f1(v[0], v[4], v[8], v[12]);
  bf4f(v[1], v[5], v[9], v[13], K1);
  bf4f(v[2], v[6], v[10], v[14], K2);
  bf4f(v[3], v[7], v[11], v[15], K3);
  bf4f1(v[0], v[1], v[2], v[3]);
  bf4f1(v[4], v[5], v[6], v[7]);
  bf4f1(v[8], v[9], v[10], v[11]);
  bf4f1(v[12], v[13], v[14], v[15]);
  // ---- spectral multiply with (K + D) (kf pre-scaled by 1/4096) ----
  {
    const float dsc = D[c] * (1.0f / 4096.0f);
    const float2* __restrict__ kfc = kf + (size_t)c * 4096 + 16 * tid;
#pragma unroll
    for (int e = 0; e < 16; ++e) {
      float2 kv = kfc[e];
      kv.x += dsc;
      v[e] = cmulf(v[e], kv);
    }
  }
  // ---- inverse phase C ----
  bf4i1(v[0], v[1], v[2], v[3]);
  bf4i1(v[4], v[5], v[6], v[7]);
  bf4i1(v[8], v[9], v[10], v[11]);
  bf4i1(v[12], v[13], v[14], v[15]);
  bf4i1(v[0], v[4], v[8], v[12]);
  bf4i(v[1], v[5], v[9], v[13], cconj(K1));
  bf4i(v[2], v[6], v[10], v[14], cconj(K2));
  bf4i(v[3], v[7], v[11], v[15], cconj(K3));
  // ---- exchange 3 ----
#pragma unroll
  for (int e = 0; e < 16; ++e) s[17 * tid + e] = v[e];
  __syncthreads();
#pragma unroll
  for (int e = 0; e < 16; ++e) v[e] = s[rbB + 17 * e];
  // ---- inverse phase B ----
  sincospif((float)b_ * (1.0f / 32.0f), &sv, &cv);
  {
    const float2 w16c = make_float2(cv, sv);
    bf4i(v[0], v[1], v[2], v[3], w16c);
    bf4i(v[4], v[5], v[6], v[7], w16c);
    bf4i(v[8], v[9], v[10], v[11], w16c);
    bf4i(v[12], v[13], v[14], v[15], w16c);
  }
  sincospif((float)b_ * (1.0f / 128.0f), &sv, &cv);
  {
    const float2 wbc = make_float2(cv, sv);
    bf4i(v[0], v[4], v[8], v[12], wbc);
    bf4i(v[1], v[5], v[9], v[13], cmulf(wbc, cconj(K1)));
    bf4i(v[2], v[6], v[10], v[14], cmulf(wbc, cconj(K2)));
    bf4i(v[3], v[7], v[11], v[15], cmulf(wbc, cconj(K3)));
  }
  // ---- exchange 4 ----
#pragma unroll
  for (int e = 0; e < 16; ++e) s[rbB + 17 * e] = v[e];
  __syncthreads();
  {
    const int wb0 = tid + (tid >> 4);
#pragma unroll
    for (int e = 0; e < 16; ++e) v[e] = s[272 * e + wb0];
  }
  // ---- inverse phase A: Q=256, then Q=1024 fused with GELU + bf16 store ----
  sincospif((float)tid * (1.0f / 512.0f), &sv, &cv);
  {
    const float2 wqc = make_float2(cv, sv);
    bf4i(v[0], v[1], v[2], v[3], wqc);
    bf4i(v[4], v[5], v[6], v[7], wqc);
    bf4i(v[8], v[9], v[10], v[11], wqc);
    bf4i(v[12], v[13], v[14], v[15], wqc);
  }
  sincospif((float)tid * (1.0f / 2048.0f), &sv, &cv);
  const float2 wtc = make_float2(cv, sv);
  auto fin = [&](float2 va, float2 vb, float2 vc2, float2 vd, float2 u1, int e0) {
    float2 u2 = cmulf(u1, u1);
    float2 tb = cmulf(vb, u2), td = cmulf(vd, u2);
    float2 a1 = cadd(va, tb), b1 = csub(va, tb), c1 = cadd(vc2, td), d1 = csub(vc2, td);
    float2 tc = cmulf(c1, u1), te = cmulf(d1, u1);
    float2 oa = cadd(a1, tc);
    float2 ob = make_float2(b1.x - te.y, b1.y + te.x);
    int i0 = tid + 256 * e0;
    hb1[i0] = f2bf(gelu1(oa.x));
    hb2[i0] = f2bf(gelu1(oa.y));
    hb1[i0 + 1024] = f2bf(gelu1(ob.x));
    hb2[i0 + 1024] = f2bf(gelu1(ob.y));
  };
  fin(v[0], v[4], v[8], v[12], wtc, 0);
  fin(v[1], v[5], v[9], v[13], cmulf(wtc, cconj(K1)), 1);
  fin(v[2], v[6], v[10], v[14], cmulf(wtc, cconj(K2)), 2);
  fin(v[3], v[7], v[11], v[15], cmulf(wtc, cconj(K3)), 3);
}

// ---------------------------------------------------------------------------
// Kernel 4 (MFMA bf16): out[b,t,o] = sum_c h[b,c,t]*W[o,c] + b_out[o] + x[b,t,o]
// Direct epilogue stores from the accumulator layout (no LDS round-trip).
// ---------------------------------------------------------------------------
__global__ __launch_bounds__(256) void k_out(const ushort_t* __restrict__ h_bf,
                                             const float* __restrict__ W,
                                             const float* __restrict__ bout,
                                             const float* __restrict__ x,
                                             float* __restrict__ out) {
  __shared__ __align__(16) char smem[52224];
  ushort_t* Wl = (ushort_t*)smem;                  // [128][136]
  ushort_t* hl = (ushort_t*)(smem + 34816);        // [64][136]
  const int tid = threadIdx.x;
  const int b = blockIdx.x >> 5;
  const int t0 = (blockIdx.x & 31) << 6;

  // stage W (fp32 -> bf16, swizzled: col' = ((cb ^ (o&15))<<3) + (c&7))
  {
    const float4* __restrict__ W4 = (const float4*)W;
#pragma unroll
    for (int r = 0; r < 16; ++r) {
      int idx = tid + 256 * r;  // 128 o x 32 j
      int o = idx >> 5, j = idx & 31;
      float4 w4 = W4[o * 32 + j];
      int sc = (((j >> 1) ^ (o & 15)) << 3) + 4 * (j & 1);
      ushort4 u;
      u.x = f2bf(w4.x); u.y = f2bf(w4.y); u.z = f2bf(w4.z); u.w = f2bf(w4.w);
      *(ushort4*)&Wl[o * 136 + sc] = u;
    }
  }
  // stage h tile (bf16 global (b,c,t) -> LDS [t][c] swizzled)
  {
#pragma unroll
    for (int r = 0; r < 8; ++r) {
      int idx = tid + 256 * r;  // 128 c x 16 t4
      int cc = idx >> 4, t4 = (idx & 15) * 4;
      ushort4 hv = *(const ushort4*)&h_bf[((size_t)(b * 128 + cc)) * 2048 + t0 + t4];
      int cb = cc >> 3, clo = cc & 7;
#pragma unroll
      for (int i = 0; i < 4; ++i) {
        int t = t4 + i;
        hl[t * 136 + (((cb ^ (t & 15)) << 3) + clo)] = ((const ushort_t*)&hv)[i];
      }
    }
  }
  __syncthreads();

  const int l = tid & 63;
  const int w = tid >> 6;
  const int tl = l & 15;
  const int g = l >> 4;
  f32x4 acc[8];
#pragma unroll
  for (int i = 0; i < 8; ++i) acc[i] = (f32x4){0.f, 0.f, 0.f, 0.f};

#pragma unroll
  for (int ks = 0; ks < 4; ++ks) {
    int cb = ks * 4 + g;
    int col = ((cb ^ tl) << 3);
    bf16x8 bfrag = *(const bf16x8*)&hl[(16 * w + tl) * 136 + col];
#pragma unroll
    for (int ot = 0; ot < 8; ++ot) {
      bf16x8 afrag = *(const bf16x8*)&Wl[(ot * 16 + tl) * 136 + col];
      acc[ot] = __builtin_amdgcn_mfma_f32_16x16x32_bf16(afrag, bfrag, acc[ot], 0, 0, 0);
    }
  }
  // direct epilogue: acc[ot][r] = out[o=16ot+4g+r][t=16w+tl]
  const int t = t0 + 16 * w + tl;
  const size_t rowoff = ((size_t)b * 2048 + t) * 128;
#pragma unroll
  for (int ot = 0; ot < 8; ++ot) {
    int o = ot * 16 + g * 4;
    float4 xv = *(const float4*)&x[rowoff + o];
    float4 bo4 = *(const float4*)&bout[o];
    float4 v;
    v.x = acc[ot][0] + bo4.x + xv.x;
    v.y = acc[ot][1] + bo4.y + xv.y;
    v.z = acc[ot][2] + bo4.z + xv.z;
    v.w = acc[ot][3] + bo4.w + xv.w;
    *(float4*)&out[rowoff + o] = v;
  }
}

// ---------------------------------------------------------------------------

extern "C" void kernel_launch(void* const* d_in, const int* in_sizes, int n_in,
                              void* d_out, int out_size, void* d_ws, size_t ws_size,
                              hipStream_t stream) {
  (void)in_sizes; (void)n_in; (void)out_size; (void)ws_size;
  const float* x  = (const float*)d_in[0];
  const float* g  = (const float*)d_in[1];
  const float* be = (const float*)d_in[2];
  const float* Lr = (const float*)d_in[3];
  const float* Li = (const float*)d_in[4];
  const float* Pr = (const float*)d_in[5];
  const float* Pi = (const float*)d_in[6];
  const float* Br = (const float*)d_in[7];
  const float* Bi = (const float*)d_in[8];
  const float* Cr = (const float*)d_in[9];
  const float* Ci = (const float*)d_in[10];
  const float* D  = (const float*)d_in[11];
  const float* W  = (const float*)d_in[12];
  const float* bo = (const float*)d_in[13];
  float* out = (float*)d_out;

  char* ws = (char*)d_ws;
  ushort_t* y_bf = (ushort_t*)ws;                 //  8 MiB: y bf16 (B,C,T)
  float2*   arr  = (float2*)(ws + (16u << 20));   //  2 MiB: at_roots (C,L)
  float2*   kfb  = (float2*)(ws + (18u << 20));   //  4 MiB: kernel spectrum
  ushort_t* h_bf = (ushort_t*)(ws + (22u << 20)); //  8 MiB: h bf16 (B,C,T)

  hipLaunchKernelGGL(k_ln_ar, dim3(1536), dim3(256), 0, stream,
                     x, g, be, y_bf, Lr, Li, Pr, Pi, Br, Bi, Cr, Ci, arr);
  hipLaunchKernelGGL(k_kf,   dim3(128),  dim3(512), 0, stream, arr, kfb);
  hipLaunchKernelGGL(k_conv, dim3(1024), dim3(256), 0, stream, y_bf, kfb, D, h_bf);
  hipLaunchKernelGGL(k_out,  dim3(512),  dim3(256), 0, stream, h_bf, W, bo, x, out);
}

// Round 8
// 70.444 us; speedup vs baseline: 2.2898x; 1.0931x over previous
//
#include <hip/hip_runtime.h>

// ---------------------------------------------------------------------------
// Problem constants: B=16, T=2048, C=128, N=64, FFT length NF=4096
// ---------------------------------------------------------------------------

#define PAD(i) ((i) + ((i) >> 4))

using bf16x8 = __attribute__((ext_vector_type(8))) short;
using f32x4 = __attribute__((ext_vector_type(4))) float;
typedef unsigned short ushort_t;

static __device__ __forceinline__ float2 cmulf(float2 a, float2 b) {
  return make_float2(a.x * b.x - a.y * b.y, a.x * b.y + a.y * b.x);
}
static __device__ __forceinline__ float2 cadd(float2 a, float2 b) { return make_float2(a.x + b.x, a.y + b.y); }
static __device__ __forceinline__ float2 csub(float2 a, float2 b) { return make_float2(a.x - b.x, a.y - b.y); }
static __device__ __forceinline__ float2 cconj(float2 a) { return make_float2(a.x, -a.y); }
static __device__ __forceinline__ float gelu1(float x) { return 0.5f * x * (1.0f + erff(x * 0.70710678f)); }
static __device__ __forceinline__ ushort_t f2bf(float f) {  // RNE f32->bf16
  unsigned int u = __float_as_uint(f);
  u += 0x7FFFu + ((u >> 16) & 1u);
  return (ushort_t)(u >> 16);
}
static __device__ __forceinline__ float bf2f(ushort_t u) {
  return __uint_as_float(((unsigned int)u) << 16);
}
// Hardware twiddles: v_sin/v_cos take input in REVOLUTIONS (D = sin(2*pi*S0)).
// All FFT twiddle angles are exact revolution fractions in [0,1) -> valid range.
static __device__ __forceinline__ float2 twf(float rev) {  // e^{-2*pi*i*rev}
  return make_float2(__builtin_amdgcn_cosf(rev), -__builtin_amdgcn_sinf(rev));
}
static __device__ __forceinline__ float2 twi(float rev) {  // e^{+2*pi*i*rev}
  return make_float2(__builtin_amdgcn_cosf(rev), __builtin_amdgcn_sinf(rev));
}

template <bool INV>
static __device__ __forceinline__ void bf4g(float2& a, float2& b, float2& c, float2& d, float2 w1) {
  float2 t0 = cadd(a, c), t1 = csub(a, c), t2 = cadd(b, d), t3 = csub(b, d);
  float2 w2 = cmulf(w1, w1), w3 = cmulf(w2, w1);
  float2 o0 = cadd(t0, t2);
  float2 o1 = cmulf(csub(t0, t2), w2);
  float2 o2, o3;
  if (!INV) {
    o2 = cmulf(make_float2(t1.x + t3.y, t1.y - t3.x), w1);
    o3 = cmulf(make_float2(t1.x - t3.y, t1.y + t3.x), w3);
  } else {
    o2 = cmulf(make_float2(t1.x - t3.y, t1.y + t3.x), w1);
    o3 = cmulf(make_float2(t1.x + t3.y, t1.y - t3.x), w3);
  }
  a = o0; b = o1; c = o2; d = o3;
}
static __device__ __forceinline__ void bf4f(float2& a, float2& b, float2& c, float2& d, float2 w1) {
  bf4g<false>(a, b, c, d, w1);
}
static __device__ __forceinline__ void bf4f1(float2& a, float2& b, float2& c, float2& d) {
  float2 t0 = cadd(a, c), t1 = csub(a, c), t2 = cadd(b, d), t3 = csub(b, d);
  a = cadd(t0, t2);
  b = csub(t0, t2);
  c = make_float2(t1.x + t3.y, t1.y - t3.x);
  d = make_float2(t1.x - t3.y, t1.y + t3.x);
}
static __device__ __forceinline__ void bf4f_z(float2 a, float2 b, float2 w1,
                                              float2& o0, float2& o1, float2& o2, float2& o3) {
  float2 w2 = cmulf(w1, w1), w3 = cmulf(w2, w1);
  o0 = cadd(a, b);
  o1 = cmulf(csub(a, b), w2);
  o2 = cmulf(make_float2(a.x + b.y, a.y - b.x), w1);
  o3 = cmulf(make_float2(a.x - b.y, a.y + b.x), w3);
}
template <bool INV>
static __device__ __forceinline__ void bf4h(float2& a, float2& b, float2& c, float2& d, float2 u1) {
  float2 u2 = cmulf(u1, u1);
  float2 tb = cmulf(b, u2), td = cmulf(d, u2);
  float2 a1 = cadd(a, tb), b1 = csub(a, tb), c1 = cadd(c, td), d1 = csub(c, td);
  float2 tc = cmulf(c1, u1), te = cmulf(d1, u1);
  a = cadd(a1, tc);
  c = csub(a1, tc);
  if (INV) {
    b = make_float2(b1.x - te.y, b1.y + te.x);
    d = make_float2(b1.x + te.y, b1.y - te.x);
  } else {
    b = make_float2(b1.x + te.y, b1.y - te.x);
    d = make_float2(b1.x - te.y, b1.y + te.x);
  }
}
static __device__ __forceinline__ void bf4i(float2& a, float2& b, float2& c, float2& d, float2 u1) {
  bf4h<true>(a, b, c, d, u1);
}
static __device__ __forceinline__ void bf4i1(float2& a, float2& b, float2& c, float2& d) {
  float2 a1 = cadd(a, b), b1 = csub(a, b), c1 = cadd(c, d), d1 = csub(c, d);
  a = cadd(a1, c1);
  c = csub(a1, c1);
  b = make_float2(b1.x - d1.y, b1.y + d1.x);
  d = make_float2(b1.x + d1.y, b1.y - d1.x);
}

#define W256R 0.9238795325112867f
#define W256I -0.3826834323650898f
#define W512R 0.7071067811865476f
#define W512I -0.7071067811865476f
#define W768R 0.3826834323650898f
#define W768I -0.9238795325112867f

// ---------------------------------------------------------------------------
// Kernel 1 (fused): blocks [0,1024): LayerNorm+transpose (B,T,C)->(B,C,T) bf16.
//                   blocks [1024,2048): at_roots Cauchy sums (1 root/thread).
// ---------------------------------------------------------------------------
__global__ __launch_bounds__(256) void k_ln_ar(
    const float* __restrict__ x, const float* __restrict__ gamma, const float* __restrict__ beta,
    ushort_t* __restrict__ y_bf,
    const float* __restrict__ Lr, const float* __restrict__ Li,
    const float* __restrict__ Pr, const float* __restrict__ Pi,
    const float* __restrict__ Br, const float* __restrict__ Bi,
    const float* __restrict__ Cr, const float* __restrict__ Ci,
    float2* __restrict__ arr) {
  __shared__ __align__(16) char sm[17536];
  const int tid = threadIdx.x;
  if (blockIdx.x < 1024) {
    // ---------------- LayerNorm + transpose ----------------
    float* tile = (float*)sm;              // [32*129]
    float* sg = (float*)(sm + 16512);      // [128]
    float* sb = (float*)(sm + 17024);      // [128]
    const int b = blockIdx.x >> 6;
    const int t0 = (blockIdx.x & 63) << 5;
    if (tid < 128) { sg[tid] = gamma[tid]; sb[tid] = beta[tid]; }
    const float4* __restrict__ xb4 = (const float4*)(x + ((size_t)b * 2048 + t0) * 128);
#pragma unroll
    for (int r = 0; r < 4; ++r) {
      int idx = tid + 256 * r;  // 32 t x 32 j
      int t = idx >> 5, j = idx & 31;
      float4 v4 = xb4[idx];
      float* dst = &tile[t * 129 + 4 * j];
      dst[0] = v4.x; dst[1] = v4.y; dst[2] = v4.z; dst[3] = v4.w;
    }
    __syncthreads();
    const int row = tid >> 3, sgp = tid & 7;
    float sum = 0.f, sq = 0.f;
#pragma unroll
    for (int i = 0; i < 16; ++i) {
      float v = tile[row * 129 + sgp * 16 + i];
      sum += v;
      sq += v * v;
    }
    sum += __shfl_xor(sum, 1); sq += __shfl_xor(sq, 1);
    sum += __shfl_xor(sum, 2); sq += __shfl_xor(sq, 2);
    sum += __shfl_xor(sum, 4); sq += __shfl_xor(sq, 4);
    float mean = sum * (1.0f / 128.0f);
    float var = sq * (1.0f / 128.0f) - mean * mean;
    float rstd = 1.0f / sqrtf(var + 1e-5f);
#pragma unroll
    for (int i = 0; i < 16; ++i) {
      int cc = sgp * 16 + i;
      float v = tile[row * 129 + cc];
      tile[row * 129 + cc] = (v - mean) * rstd * sg[cc] + sb[cc];
    }
    __syncthreads();
    ushort_t* __restrict__ yb = y_bf + (size_t)b * 128 * 2048 + t0;
#pragma unroll
    for (int r = 0; r < 4; ++r) {
      int idx = tid + 256 * r;  // 128 cc x 8 tl4
      int cc = idx >> 3, tl4 = (idx & 7) * 4;
      ushort4 o4;
      o4.x = f2bf(tile[(tl4 + 0) * 129 + cc]);
      o4.y = f2bf(tile[(tl4 + 1) * 129 + cc]);
      o4.z = f2bf(tile[(tl4 + 2) * 129 + cc]);
      o4.w = f2bf(tile[(tl4 + 3) * 129 + cc]);
      *(ushort4*)(yb + (size_t)cc * 2048 + tl4) = o4;
    }
  } else {
    // ---------------- at_roots (DPLR generating function) ----------------
    // NOTE: Omega must use the APPROXIMATE angle (sincosf of theta) exactly
    // like the JAX reference; exact trig makes 1+Omega==0 at l=1024 -> NaN.
    float2* sLam = (float2*)sm;
    float2* sv00 = sLam + 64;
    float2* sv01 = sLam + 128;
    float2* sv10 = sLam + 192;
    float2* sv11 = sLam + 256;
    const int id = blockIdx.x - 1024;  // [0,1024)
    const int c = id >> 3;
    const int l = ((id & 7) << 8) + tid;
    if (tid < 64) {
      int i = c * 64 + tid;
      float lr = fminf(Lr[i], 1e-4f), li = Li[i];
      float pr = Pr[i], pi = Pi[i];
      float br = Br[i], bi = Bi[i];
      float cr = Cr[i], ci = Ci[i];
      sLam[tid] = make_float2(lr, li);
      sv00[tid] = make_float2(cr * br + ci * bi, cr * bi - ci * br);
      sv01[tid] = make_float2(cr * pr + ci * pi, cr * pi - ci * pr);
      sv10[tid] = make_float2(pr * br + pi * bi, pr * bi - pi * br);
      sv11[tid] = make_float2(pr * pr + pi * pi, 0.0f);
    }
    __syncthreads();
    float theta = (-6.2831855f * (float)l) * (1.0f / 2048.0f);
    float om_i, om_r;
    sincosf(theta, &om_i, &om_r);
    float pr_ = 1.0f + om_r, pi_ = om_i;
    float mr_ = 1.0f - om_r, mi_ = -om_i;
    float invd = __builtin_amdgcn_rcpf(fmaf(pr_, pr_, pi_ * pi_));
    float gr = 200.0f * ((mr_ * pr_ + mi_ * pi_) * invd);
    float gi = 200.0f * ((mi_ * pr_ - mr_ * pi_) * invd);
    float c2r = 2.0f * pr_ * invd, c2i = -2.0f * pi_ * invd;
    float s00r = 0.f, s00i = 0.f, s01r = 0.f, s01i = 0.f;
    float s10r = 0.f, s10i = 0.f, s11r = 0.f, s11i = 0.f;
#pragma unroll 8
    for (int n = 0; n < 64; ++n) {
      float2 lam = sLam[n];
      float dr = gr - lam.x, di = gi - lam.y;
      float idn = __builtin_amdgcn_rcpf(fmaf(dr, dr, di * di));
      float ir = dr * idn, ii = -di * idn;
      float2 v;
      v = sv00[n]; s00r += v.x * ir - v.y * ii; s00i += v.x * ii + v.y * ir;
      v = sv01[n]; s01r += v.x * ir - v.y * ii; s01i += v.x * ii + v.y * ir;
      v = sv10[n]; s10r += v.x * ir - v.y * ii; s10i += v.x * ii + v.y * ir;
      v = sv11[n]; s11r += v.x * ir - v.y * ii; s11i += v.x * ii + v.y * ir;
    }
    float dr2 = 1.0f + s11r, di2 = s11i;
    float idn2 = __builtin_amdgcn_rcpf(fmaf(dr2, dr2, di2 * di2));
    float rr = dr2 * idn2, ri = -di2 * idn2;
    float t1r = s01r * rr - s01i * ri, t1i = s01r * ri + s01i * rr;
    float t2r = t1r * s10r - t1i * s10i, t2i = t1r * s10i + t1i * s10r;
    float fr = s00r - t2r, fi = s00i - t2i;
    arr[(size_t)c * 2048 + l] = make_float2(c2r * fr - c2i * fi, c2r * fi + c2i * fr);
  }
}

// ---------------------------------------------------------------------------
// Kernel 2: kf via even/odd-bin split. 512 threads/block, HW twiddles.
// ---------------------------------------------------------------------------
template <int Q, bool INV>
static __device__ __forceinline__ void kfs_dif(float2* s, int tid) {
  constexpr float SCR = (float)(2048 / (4 * Q)) * (1.0f / 2048.0f);  // revolutions
  int k = tid;  // [0,512)
  int j = k & (Q - 1);
  int i = ((k - j) << 2) + j;
  float2 w1 = INV ? twi((float)j * SCR) : twf((float)j * SCR);
  float2 a = s[PAD(i)], b = s[PAD(i + Q)], c2 = s[PAD(i + 2 * Q)], d = s[PAD(i + 3 * Q)];
  bf4g<INV>(a, b, c2, d, w1);
  s[PAD(i)] = a; s[PAD(i + Q)] = b; s[PAD(i + 2 * Q)] = c2; s[PAD(i + 3 * Q)] = d;
  __syncthreads();
}
template <int Q>
static __device__ __forceinline__ void kfs_dit(float2* s, int tid) {
  constexpr float SCR = (float)(2048 / (4 * Q)) * (1.0f / 2048.0f);
  int k = tid;
  int j = k & (Q - 1);
  int i = ((k - j) << 2) + j;
  float2 u1 = twf((float)j * SCR);
  float2 a = s[PAD(i)], b = s[PAD(i + Q)], c2 = s[PAD(i + 2 * Q)], d = s[PAD(i + 3 * Q)];
  bf4h<false>(a, b, c2, d, u1);
  s[PAD(i)] = a; s[PAD(i + Q)] = b; s[PAD(i + 2 * Q)] = c2; s[PAD(i + 3 * Q)] = d;
  __syncthreads();
}
static __device__ __forceinline__ void kfs_r2(float2* s, int tid) {
#pragma unroll
  for (int m = 0; m < 2; ++m) {
    int k = tid + 512 * m;  // [0,1024)
    int i = 2 * k;
    float2 a = s[PAD(i)], b = s[PAD(i + 1)];
    s[PAD(i)] = cadd(a, b);
    s[PAD(i + 1)] = csub(a, b);
  }
  __syncthreads();
}

__global__ __launch_bounds__(512) void k_kf(const float2* __restrict__ arr, float2* __restrict__ kf) {
  __shared__ float2 s[2176];
  const int tid = threadIdx.x;
  const int c = blockIdx.x;
  const float2* __restrict__ ac = arr + (size_t)c * 2048;
  float2* __restrict__ kfc = kf + (size_t)c * 4096;
#pragma unroll
  for (int m = 0; m < 4; ++m) {
    int q = tid + 512 * m;
    float2 aq = ac[q];
    s[PAD(q)] = aq;
    float2 am = ac[(2048 - q) & 2047];
    kfc[__brev((unsigned)q) >> 21] =
        make_float2((aq.x + am.x) * (0.5f / 4096.0f), (aq.y - am.y) * (0.5f / 4096.0f));
  }
  __syncthreads();
  kfs_dif<512, true>(s, tid);
  kfs_dif<128, true>(s, tid);
  kfs_dif<32, true>(s, tid);
  kfs_dif<8, true>(s, tid);
  kfs_dif<2, true>(s, tid);
  kfs_r2(s, tid);
#pragma unroll
  for (int m = 0; m < 4; ++m) {
    int p = tid + 512 * m;
    int t = (int)(__brev((unsigned)p) >> 21);
    float2 w = twf((float)t * (1.0f / 4096.0f));
    float kr = s[PAD(p)].x * (1.0f / 8388608.0f);
    s[PAD(p)] = make_float2(kr * w.x, kr * w.y);
  }
  __syncthreads();
  kfs_r2(s, tid);
  kfs_dit<2>(s, tid);
  kfs_dit<8>(s, tid);
  kfs_dit<32>(s, tid);
  kfs_dit<128>(s, tid);
  kfs_dit<512>(s, tid);
#pragma unroll
  for (int m = 0; m < 4; ++m) {
    int q = tid + 512 * m;
    kfc[2048 + (int)(__brev((unsigned)q) >> 21)] = s[PAD(q)];
  }
}

// ---------------------------------------------------------------------------
// Kernel 3: paired real FFT conv (y bf16), 3-level register FFT, HW twiddles;
// D*y folded into spectrum; writes h as bf16 (B,C,T).
// ---------------------------------------------------------------------------
__global__ __launch_bounds__(256) void k_conv(const ushort_t* __restrict__ y_bf,
                                              const float2* __restrict__ kf,
                                              const float* __restrict__ D,
                                              ushort_t* __restrict__ h_bf) {
  __shared__ float2 s[4352];
  const int tid = threadIdx.x;
  const int p = blockIdx.x;
  const int b = p >> 7, c = p & 127;
  const ushort_t* __restrict__ r1 = y_bf + (size_t)(b * 128 + c) * 2048;
  const ushort_t* __restrict__ r2 = y_bf + (size_t)((b + 8) * 128 + c) * 2048;
  ushort_t* __restrict__ hb1 = h_bf + (size_t)(b * 128 + c) * 2048;
  ushort_t* __restrict__ hb2 = h_bf + (size_t)((b + 8) * 128 + c) * 2048;

  const float2 K1 = make_float2(W256R, W256I);
  const float2 K2 = make_float2(W512R, W512I);
  const float2 K3 = make_float2(W768R, W768I);

  float2 v[16];
  // ---- forward phase A: Q=1024 (legs 2,3 zero), Q=256 ----
  {
    float2 ya[8];
#pragma unroll
    for (int e = 0; e < 8; ++e)
      ya[e] = make_float2(bf2f(r1[tid + 256 * e]), bf2f(r2[tid + 256 * e]));
    const float2 wt = twf((float)tid * (1.0f / 4096.0f));
    bf4f_z(ya[0], ya[4], wt,            v[0], v[4], v[8], v[12]);
    bf4f_z(ya[1], ya[5], cmulf(wt, K1), v[1], v[5], v[9], v[13]);
    bf4f_z(ya[2], ya[6], cmulf(wt, K2), v[2], v[6], v[10], v[14]);
    bf4f_z(ya[3], ya[7], cmulf(wt, K3), v[3], v[7], v[11], v[15]);
  }
  {
    const float2 wq = twf((float)tid * (1.0f / 1024.0f));
    bf4f(v[0], v[1], v[2], v[3], wq);
    bf4f(v[4], v[5], v[6], v[7], wq);
    bf4f(v[8], v[9], v[10], v[11], wq);
    bf4f(v[12], v[13], v[14], v[15], wq);
  }
  // ---- exchange 1: write A-pattern, read B-pattern ----
  {
    const int wb0 = tid + (tid >> 4);
#pragma unroll
    for (int e = 0; e < 16; ++e) s[272 * e + wb0] = v[e];
  }
  __syncthreads();
  const int a_ = tid >> 4, b_ = tid & 15;
  const int rbB = 272 * a_ + b_;
#pragma unroll
  for (int e = 0; e < 16; ++e) v[e] = s[rbB + 17 * e];
  // ---- forward phase B: Q=64, Q=16 ----
  {
    const float2 wb = twf((float)b_ * (1.0f / 256.0f));
    bf4f(v[0], v[4], v[8], v[12], wb);
    bf4f(v[1], v[5], v[9], v[13], cmulf(wb, K1));
    bf4f(v[2], v[6], v[10], v[14], cmulf(wb, K2));
    bf4f(v[3], v[7], v[11], v[15], cmulf(wb, K3));
  }
  {
    const float2 w16 = twf((float)b_ * (1.0f / 64.0f));
    bf4f(v[0], v[1], v[2], v[3], w16);
    bf4f(v[4], v[5], v[6], v[7], w16);
    bf4f(v[8], v[9], v[10], v[11], w16);
    bf4f(v[12], v[13], v[14], v[15], w16);
  }
  // ---- exchange 2 ----
#pragma unroll
  for (int e = 0; e < 16; ++e) s[rbB + 17 * e] = v[e];
  __syncthreads();
#pragma unroll
  for (int e = 0; e < 16; ++e) v[e] = s[17 * tid + e];
  // ---- forward phase C ----
  bf4f1(v[0], v[4], v[8], v[12]);
  bf4f(v[1], v[5], v[9], v[13], K1);
  bf4f(v[2], v[6], v[10], v[14], K2);
  bf4f(v[3], v[7], v[11], v[15], K3);
  bf4f1(v[0], v[1], v[2], v[3]);
  bf4f1(v[4], v[5], v[6], v[7]);
  bf4f1(v[8], v[9], v[10], v[11]);
  bf4f1(v[12], v[13], v[14], v[15]);
  // ---- spectral multiply with (K + D) (kf pre-scaled by 1/4096) ----
  {
    const float dsc = D[c] * (1.0f / 4096.0f);
    const float2* __restrict__ kfc = kf + (size_t)c * 4096 + 16 * tid;
#pragma unroll
    for (int e = 0; e < 16; ++e) {
      float2 kv = kfc[e];
      kv.x += dsc;
      v[e] = cmulf(v[e], kv);
    }
  }
  // ---- inverse phase C ----
  bf4i1(v[0], v[1], v[2], v[3]);
  bf4i1(v[4], v[5], v[6], v[7]);
  bf4i1(v[8], v[9], v[10], v[11]);
  bf4i1(v[12], v[13], v[14], v[15]);
  bf4i1(v[0], v[4], v[8], v[12]);
  bf4i(v[1], v[5], v[9], v[13], cconj(K1));
  bf4i(v[2], v[6], v[10], v[14], cconj(K2));
  bf4i(v[3], v[7], v[11], v[15], cconj(K3));
  // ---- exchange 3 ----
#pragma unroll
  for (int e = 0; e < 16; ++e) s[17 * tid + e] = v[e];
  __syncthreads();
#pragma unroll
  for (int e = 0; e < 16; ++e) v[e] = s[rbB + 17 * e];
  // ---- inverse phase B ----
  {
    const float2 w16c = twi((float)b_ * (1.0f / 64.0f));
    bf4i(v[0], v[1], v[2], v[3], w16c);
    bf4i(v[4], v[5], v[6], v[7], w16c);
    bf4i(v[8], v[9], v[10], v[11], w16c);
    bf4i(v[12], v[13], v[14], v[15], w16c);
  }
  {
    const float2 wbc = twi((float)b_ * (1.0f / 256.0f));
    bf4i(v[0], v[4], v[8], v[12], wbc);
    bf4i(v[1], v[5], v[9], v[13], cmulf(wbc, cconj(K1)));
    bf4i(v[2], v[6], v[10], v[14], cmulf(wbc, cconj(K2)));
    bf4i(v[3], v[7], v[11], v[15], cmulf(wbc, cconj(K3)));
  }
  // ---- exchange 4 ----
#pragma unroll
  for (int e = 0; e < 16; ++e) s[rbB + 17 * e] = v[e];
  __syncthreads();
  {
    const int wb0 = tid + (tid >> 4);
#pragma unroll
    for (int e = 0; e < 16; ++e) v[e] = s[272 * e + wb0];
  }
  // ---- inverse phase A: Q=256, then Q=1024 fused with GELU + bf16 store ----
  {
    const float2 wqc = twi((float)tid * (1.0f / 1024.0f));
    bf4i(v[0], v[1], v[2], v[3], wqc);
    bf4i(v[4], v[5], v[6], v[7], wqc);
    bf4i(v[8], v[9], v[10], v[11], wqc);
    bf4i(v[12], v[13], v[14], v[15], wqc);
  }
  const float2 wtc = twi((float)tid * (1.0f / 4096.0f));
  auto fin = [&](float2 va, float2 vb, float2 vc2, float2 vd, float2 u1, int e0) {
    float2 u2 = cmulf(u1, u1);
    float2 tb = cmulf(vb, u2), td = cmulf(vd, u2);
    float2 a1 = cadd(va, tb), b1 = csub(va, tb), c1 = cadd(vc2, td), d1 = csub(vc2, td);
    float2 tc = cmulf(c1, u1), te = cmulf(d1, u1);
    float2 oa = cadd(a1, tc);
    float2 ob = make_float2(b1.x - te.y, b1.y + te.x);
    int i0 = tid + 256 * e0;
    hb1[i0] = f2bf(gelu1(oa.x));
    hb2[i0] = f2bf(gelu1(oa.y));
    hb1[i0 + 1024] = f2bf(gelu1(ob.x));
    hb2[i0 + 1024] = f2bf(gelu1(ob.y));
  };
  fin(v[0], v[4], v[8], v[12], wtc, 0);
  fin(v[1], v[5], v[9], v[13], cmulf(wtc, cconj(K1)), 1);
  fin(v[2], v[6], v[10], v[14], cmulf(wtc, cconj(K2)), 2);
  fin(v[3], v[7], v[11], v[15], cmulf(wtc, cconj(K3)), 3);
}

// ---------------------------------------------------------------------------
// Kernel 4 (MFMA bf16): out[b,t,o] = sum_c h[b,c,t]*W[o,c] + b_out[o] + x[b,t,o]
// Direct epilogue stores from the accumulator layout (no LDS round-trip).
// ---------------------------------------------------------------------------
__global__ __launch_bounds__(256) void k_out(const ushort_t* __restrict__ h_bf,
                                             const float* __restrict__ W,
                                             const float* __restrict__ bout,
                                             const float* __restrict__ x,
                                             float* __restrict__ out) {
  __shared__ __align__(16) char smem[52224];
  ushort_t* Wl = (ushort_t*)smem;                  // [128][136]
  ushort_t* hl = (ushort_t*)(smem + 34816);        // [64][136]
  const int tid = threadIdx.x;
  const int b = blockIdx.x >> 5;
  const int t0 = (blockIdx.x & 31) << 6;

  // stage W (fp32 -> bf16, swizzled: col' = ((cb ^ (o&15))<<3) + (c&7))
  {
    const float4* __restrict__ W4 = (const float4*)W;
#pragma unroll
    for (int r = 0; r < 16; ++r) {
      int idx = tid + 256 * r;  // 128 o x 32 j
      int o = idx >> 5, j = idx & 31;
      float4 w4 = W4[o * 32 + j];
      int sc = (((j >> 1) ^ (o & 15)) << 3) + 4 * (j & 1);
      ushort4 u;
      u.x = f2bf(w4.x); u.y = f2bf(w4.y); u.z = f2bf(w4.z); u.w = f2bf(w4.w);
      *(ushort4*)&Wl[o * 136 + sc] = u;
    }
  }
  // stage h tile (bf16 global (b,c,t) -> LDS [t][c] swizzled)
  {
#pragma unroll
    for (int r = 0; r < 8; ++r) {
      int idx = tid + 256 * r;  // 128 c x 16 t4
      int cc = idx >> 4, t4 = (idx & 15) * 4;
      ushort4 hv = *(const ushort4*)&h_bf[((size_t)(b * 128 + cc)) * 2048 + t0 + t4];
      int cb = cc >> 3, clo = cc & 7;
#pragma unroll
      for (int i = 0; i < 4; ++i) {
        int t = t4 + i;
        hl[t * 136 + (((cb ^ (t & 15)) << 3) + clo)] = ((const ushort_t*)&hv)[i];
      }
    }
  }
  __syncthreads();

  const int l = tid & 63;
  const int w = tid >> 6;
  const int tl = l & 15;
  const int g = l >> 4;
  f32x4 acc[8];
#pragma unroll
  for (int i = 0; i < 8; ++i) acc[i] = (f32x4){0.f, 0.f, 0.f, 0.f};

#pragma unroll
  for (int ks = 0; ks < 4; ++ks) {
    int cb = ks * 4 + g;
    int col = ((cb ^ tl) << 3);
    bf16x8 bfrag = *(const bf16x8*)&hl[(16 * w + tl) * 136 + col];
#pragma unroll
    for (int ot = 0; ot < 8; ++ot) {
      bf16x8 afrag = *(const bf16x8*)&Wl[(ot * 16 + tl) * 136 + col];
      acc[ot] = __builtin_amdgcn_mfma_f32_16x16x32_bf16(afrag, bfrag, acc[ot], 0, 0, 0);
    }
  }
  // direct epilogue: acc[ot][r] = out[o=16ot+4g+r][t=16w+tl]
  const int t = t0 + 16 * w + tl;
  const size_t rowoff = ((size_t)b * 2048 + t) * 128;
#pragma unroll
  for (int ot = 0; ot < 8; ++ot) {
    int o = ot * 16 + g * 4;
    float4 xv = *(const float4*)&x[rowoff + o];
    float4 bo4 = *(const float4*)&bout[o];
    float4 v;
    v.x = acc[ot][0] + bo4.x + xv.x;
    v.y = acc[ot][1] + bo4.y + xv.y;
    v.z = acc[ot][2] + bo4.z + xv.z;
    v.w = acc[ot][3] + bo4.w + xv.w;
    *(float4*)&out[rowoff + o] = v;
  }
}

// ---------------------------------------------------------------------------

extern "C" void kernel_launch(void* const* d_in, const int* in_sizes, int n_in,
                              void* d_out, int out_size, void* d_ws, size_t ws_size,
                              hipStream_t stream) {
  (void)in_sizes; (void)n_in; (void)out_size; (void)ws_size;
  const float* x  = (const float*)d_in[0];
  const float* g  = (const float*)d_in[1];
  const float* be = (const float*)d_in[2];
  const float* Lr = (const float*)d_in[3];
  const float* Li = (const float*)d_in[4];
  const float* Pr = (const float*)d_in[5];
  const float* Pi = (const float*)d_in[6];
  const float* Br = (const float*)d_in[7];
  const float* Bi = (const float*)d_in[8];
  const float* Cr = (const float*)d_in[9];
  const float* Ci = (const float*)d_in[10];
  const float* D  = (const float*)d_in[11];
  const float* W  = (const float*)d_in[12];
  const float* bo = (const float*)d_in[13];
  float* out = (float*)d_out;

  char* ws = (char*)d_ws;
  ushort_t* y_bf = (ushort_t*)ws;                 //  8 MiB: y bf16 (B,C,T)
  float2*   arr  = (float2*)(ws + (16u << 20));   //  2 MiB: at_roots (C,L)
  float2*   kfb  = (float2*)(ws + (18u << 20));   //  4 MiB: kernel spectrum
  ushort_t* h_bf = (ushort_t*)(ws + (22u << 20)); //  8 MiB: h bf16 (B,C,T)

  hipLaunchKernelGGL(k_ln_ar, dim3(2048), dim3(256), 0, stream,
                     x, g, be, y_bf, Lr, Li, Pr, Pi, Br, Bi, Cr, Ci, arr);
  hipLaunchKernelGGL(k_kf,   dim3(128),  dim3(512), 0, stream, arr, kfb);
  hipLaunchKernelGGL(k_conv, dim3(1024), dim3(256), 0, stream, y_bf, kfb, D, h_bf);
  hipLaunchKernelGGL(k_out,  dim3(512),  dim3(256), 0, stream, h_bf, W, bo, x, out);
}